// Round 1
// 14326.622 us; speedup vs baseline: 2.4031x; 2.4031x over previous
//
#include <hip/hip_runtime.h>
#include <math.h>

#define T_SEQ 2000
#define BATCH 32
#define NSEG  100

typedef unsigned short bf16_t;   // raw bf16 storage
typedef unsigned int   u32;
typedef _Float16       half_t;
typedef half_t half2_t __attribute__((ext_vector_type(2)));

// whh f16 split: KP_REG k-pairs live in VGPRs, KP_LDS k-pairs in LDS.
// KP_REG + KP_LDS == 128 (256 k values). KP_REG multiple of 4.
#define KP_REG 92
#define KP_LDS 36

__device__ __forceinline__ float sigmoidf_(float x) {
    return 1.0f / (1.0f + __expf(-x));
}
__device__ __forceinline__ float tanh_(float x) {
    return 1.0f - 2.0f / (__expf(2.0f * x) + 1.0f);
}
__device__ __forceinline__ float bf2f(bf16_t u) {
    return __uint_as_float((unsigned)u << 16);
}
__device__ __forceinline__ bf16_t f2bf(float f) {   // round-to-nearest-even
    unsigned x = __float_as_uint(f);
    return (bf16_t)((x + 0x7FFFu + ((x >> 16) & 1u)) >> 16);
}
// f32 -> f16 bits (RNE via cast)
__device__ __forceinline__ u32 f2h(float f) {
    return (u32)__builtin_bit_cast(unsigned short, (half_t)f);
}
// packed f16x2 dot with f32 accumulate
__device__ __forceinline__ float dot2f(u32 w, u32 h, float acc) {
#if __has_builtin(__builtin_amdgcn_fdot2)
    return __builtin_amdgcn_fdot2(__builtin_bit_cast(half2_t, w),
                                  __builtin_bit_cast(half2_t, h), acc, false);
#else
    half2_t wv = __builtin_bit_cast(half2_t, w);
    half2_t hv = __builtin_bit_cast(half2_t, h);
    acc = fmaf((float)wv.x, (float)hv.x, acc);
    return fmaf((float)wv.y, (float)hv.y, acc);
#endif
}

// 4 consecutive elements -> float4 (fp32 or bf16 source)
__device__ __forceinline__ float4 ld4(const float* p) { return *(const float4*)p; }
__device__ __forceinline__ float4 ld4(const bf16_t* p) {
    ushort4 u = *(const ushort4*)p;
    return make_float4(bf2f(u.x), bf2f(u.y), bf2f(u.z), bf2f(u.w));
}

// ---------------------------------------------------------------------------
// ws too small -> unmistakable signature instead of a fault
// ---------------------------------------------------------------------------
__global__ void ws_guard_kernel(float* out, int n) {
    int i = blockIdx.x * blockDim.x + threadIdx.x;
    if (i < n) out[i] = 1e30f;
}

// ---------------------------------------------------------------------------
// Generic 3D transpose (fp32): in (D0,D1,D2) -> out (D0,D2,D1)
// ---------------------------------------------------------------------------
__global__ void transpose3(const float* __restrict__ in, float* __restrict__ out,
                           int D0, int D1, int D2) {
    int i = blockIdx.x * blockDim.x + threadIdx.x;
    int tot = D0 * D1 * D2;
    if (i >= tot) return;
    int d0 = i / (D1 * D2);
    int r  = i - d0 * (D1 * D2);
    int d1 = r / D2;
    int d2 = r - d1 * D2;
    out[(size_t)d0 * D1 * D2 + (size_t)d2 * D1 + d1] = in[i];
}

// ---------------------------------------------------------------------------
// Pack whhT (2, 256, 1024) f32 -> (2, 128, 1024) u32, each u32 = f16x2 over
// adjacent k (k=2kp low half, k=2kp+1 high half). RNE rounding.
// ---------------------------------------------------------------------------
__global__ __launch_bounds__(256) void pack_whh(const float* __restrict__ whhT,
                                                u32* __restrict__ w16) {
    int i = blockIdx.x * 256 + threadIdx.x;   // 0 .. 262143
    int d  = i >> 17;
    int r  = i & 131071;
    int kp = r >> 10;
    int j  = r & 1023;
    const float* base = whhT + (size_t)d * 262144;
    u32 lo = f2h(base[(size_t)(2 * kp)     * 1024 + j]);
    u32 hi = f2h(base[(size_t)(2 * kp + 1) * 1024 + j]);
    w16[i] = lo | (hi << 16);
}

// ---------------------------------------------------------------------------
// Tiled fp32-compute GEMM:  C[m,n] = sum_k A(row(m))[k]*W[n,k] + bias[n]
// MODE 1: conv im2col  A is (B,T,CIN), k = tap*CIN+c, pad=1
// MODE 2: chunk-fwd    m=(bb,r), A row = bb*T_SEQ + (t0+r)
// MODE 3: chunk-bwd    m=(bb,r), A row = bb*T_SEQ + (lens[bb]-1-(t0+r)); t<0 skip
// TA: float | bf16_t (A storage).  OUT_BF: store C as bf16.
// Tile: 256(M) x 64(N) x 32(K); 256 thr; 8x8 micro-tile.
// LDS pitches 258 / 66 keep LDS ops at <=2-way bank aliasing (free, m136).
// ---------------------------------------------------------------------------
template <int MODE, int CIN, typename TA, bool OUT_BF>
__global__ __launch_bounds__(256) void gemm_nt(
    const TA* __restrict__ A, const float* __restrict__ W,
    const float* __restrict__ bias, void* __restrict__ Cout,
    int M, int N, int K, int relu, int t0, int chunkM,
    const int* __restrict__ lens)
{
    __shared__ float As[32 * 258];
    __shared__ float Ws[32 * 66];
    const int tid    = threadIdx.x;
    const int m_base = blockIdx.x * 256;
    const int n_base = blockIdx.y * 64;
    const int m0     = (tid >> 3) * 8;   // 0..248
    const int n0     = (tid & 7) * 8;    // 0..56
    float acc[8][8] = {};

    for (int k0 = 0; k0 < K; k0 += 32) {
        // ---- stage A tile (256 rows x 32 k), 4 elems per thread-iter ----
#pragma unroll
        for (int i = 0; i < 8; ++i) {
            int f4  = i * 256 + tid;
            int row = f4 >> 3;          // 0..255
            int k4  = (f4 & 7) << 2;    // 0..28
            int gm  = m_base + row;
            int gk  = k0 + k4;
            float4 v = make_float4(0.f, 0.f, 0.f, 0.f);
            if (gm < M && gk < K) {
                if constexpr (MODE == 1) {
                    int bb  = gm / T_SEQ;
                    int tt  = gm - bb * T_SEQ;
                    int tap = gk / CIN;
                    int cc  = gk - tap * CIN;
                    int ts  = tt + tap - 1;
                    if (ts >= 0 && ts < T_SEQ)
                        v = ld4(A + ((size_t)(bb * T_SEQ + ts) * CIN + cc));
                } else {
                    int bb = gm / chunkM;
                    int r  = gm - bb * chunkM;
                    int t  = (MODE == 2) ? (t0 + r) : (lens[bb] - 1 - (t0 + r));
                    if (t >= 0 && t < T_SEQ)
                        v = ld4(A + ((size_t)(bb * T_SEQ + t) * K + gk));
                }
            }
            As[(k4 + 0) * 258 + row] = v.x;
            As[(k4 + 1) * 258 + row] = v.y;
            As[(k4 + 2) * 258 + row] = v.z;
            As[(k4 + 3) * 258 + row] = v.w;
        }
        // ---- stage W tile (64 rows x 32 k) ----
#pragma unroll
        for (int i = 0; i < 2; ++i) {
            int f4  = i * 256 + tid;
            int row = f4 >> 3;          // 0..63
            int k4  = (f4 & 7) << 2;
            int gn  = n_base + row;
            int gk  = k0 + k4;
            float4 v = make_float4(0.f, 0.f, 0.f, 0.f);
            if (gk < K)
                v = *(const float4*)(W + (size_t)gn * K + gk);
            Ws[(k4 + 0) * 66 + row] = v.x;
            Ws[(k4 + 1) * 66 + row] = v.y;
            Ws[(k4 + 2) * 66 + row] = v.z;
            Ws[(k4 + 3) * 66 + row] = v.w;
        }
        __syncthreads();
        // ---- inner product ----
#pragma unroll 8
        for (int kk = 0; kk < 32; ++kk) {
            float am[8], wn[8];
#pragma unroll
            for (int j = 0; j < 4; ++j) {
                float2 a = *(const float2*)(As + kk * 258 + m0 + 2 * j);
                am[2 * j] = a.x; am[2 * j + 1] = a.y;
                float2 w = *(const float2*)(Ws + kk * 66 + n0 + 2 * j);
                wn[2 * j] = w.x; wn[2 * j + 1] = w.y;
            }
#pragma unroll
            for (int im = 0; im < 8; ++im)
#pragma unroll
                for (int in = 0; in < 8; ++in)
                    acc[im][in] = fmaf(am[im], wn[in], acc[im][in]);
        }
        __syncthreads();
    }

    // ---- epilogue: bias (+relu) ----
    float bs[8];
#pragma unroll
    for (int j = 0; j < 8; ++j) bs[j] = bias[n_base + n0 + j];
#pragma unroll
    for (int im = 0; im < 8; ++im) {
        int gm = m_base + m0 + im;
        if (gm < M) {
            float o[8];
#pragma unroll
            for (int j = 0; j < 8; ++j) {
                float v = acc[im][j] + bs[j];
                o[j] = relu ? fmaxf(v, 0.f) : v;
            }
            if constexpr (OUT_BF) {
                bf16_t* crow = (bf16_t*)Cout + (size_t)gm * N + n_base + n0;
                ushort4 u0 = { f2bf(o[0]), f2bf(o[1]), f2bf(o[2]), f2bf(o[3]) };
                ushort4 u1 = { f2bf(o[4]), f2bf(o[5]), f2bf(o[6]), f2bf(o[7]) };
                *(ushort4*)(crow)     = u0;
                *(ushort4*)(crow + 4) = u1;
            } else {
                float* crow = (float*)Cout + (size_t)gm * N + n_base + n0;
                *(float4*)(crow)     = make_float4(o[0], o[1], o[2], o[3]);
                *(float4*)(crow + 4) = make_float4(o[4], o[5], o[6], o[7]);
            }
        }
    }
}

// ---------------------------------------------------------------------------
// LSTM recurrence, one phase of `chunk` steps. One block (512 thr) per (b,dir).
//
// whh is held ON-CHIP for the whole phase as packed f16x2 (k-pairs):
//   kp in [0, KP_REG)          -> VGPRs (2 cols/thread -> 2*KP_REG = 184 regs)
//   kp in [KP_REG, 128)        -> LDS   (KP_LDS*1024*4 = 144 KB)
// This removes the per-step 1 MB whh stream from L2 that made the previous
// version per-CU-bandwidth-bound (~7 us/step).
//
// Thread t owns gate columns j0=2t, j0+1. Per step:
//   matvec (128 fdot2/col, f32 accum) -> gs[1024] -> barrier ->
//   threads<256: gates -> c,h update -> Hout(bf16) + hp[] (h packed f16x2)
//   -> barrier.
// XpF/XpB: (B, chunk, 1024) fp32 projections (bias included); bwd rows already
// time-reversed. state: (64, 512) fp32 h|c carried across phases.
// Hout: (B, T, 512) bf16; fwd -> [0:256), bwd -> [256:512) at tau.
// ---------------------------------------------------------------------------
__global__ __launch_bounds__(512, 2) void lstm_rec_phase(
    const float* __restrict__ XpF, const float* __restrict__ XpB,
    const u32* __restrict__ whh16, const int* __restrict__ lens,
    float* __restrict__ state, bf16_t* __restrict__ Hout, int s0, int chunk)
{
    __shared__ __align__(16) u32   wlds[KP_LDS * 1024];
    __shared__ __align__(16) float gs[1024];
    __shared__ __align__(16) u32   hp[128];

    const int bd  = blockIdx.x;
    const int b   = bd >> 1;
    const int d   = bd & 1;
    const int t   = threadIdx.x;      // 0..511
    const int j0  = t * 2;
    const int len = lens[b];
    const int s1  = min(s0 + chunk, len);
    const u32* Wg = whh16 + (size_t)d * (128 * 1024);

    // ---- load whh f16x2: registers (kp < KP_REG) + LDS (rest) ----
    u32 wa[KP_REG], wb[KP_REG];       // wa: col j0, wb: col j0+1
#pragma unroll
    for (int kp = 0; kp < KP_REG; ++kp) {
        uint2 v = *(const uint2*)(Wg + (size_t)kp * 1024 + j0);
        wa[kp] = v.x; wb[kp] = v.y;
    }
#pragma unroll 4
    for (int kpl = 0; kpl < KP_LDS; ++kpl)
        *(uint2*)(wlds + kpl * 1024 + j0) =
            *(const uint2*)(Wg + (size_t)(KP_REG + kpl) * 1024 + j0);

    // ---- init state + packed h ----
    float* st = state + bd * 512;
    float c = 0.f, hcur = 0.f;
    if (t < 256) {
        if (s0 > 0) { hcur = st[t]; c = st[256 + t]; }
        u32 hb = f2h(hcur);
        u32 ob = (u32)__shfl_xor((int)hb, 1);
        if (!(t & 1)) hp[t >> 1] = hb | (ob << 16);
    }
    __syncthreads();

    const float* xrow = ((d ? XpB : XpF) + (size_t)b * ((size_t)chunk * 1024));
    for (int s = s0; s < s1; ++s, xrow += 1024) {
        float2 xv = *(const float2*)(xrow + j0);   // issued early, used late
        float a0 = 0.f, a1 = 0.f, b0 = 0.f, b1 = 0.f;
#pragma unroll
        for (int kq = 0; kq < KP_REG / 4; ++kq) {          // 23 iters
            uint4 H = *(const uint4*)(hp + 4 * kq);
            a0 = dot2f(wa[4 * kq + 0], H.x, a0); a1 = dot2f(wb[4 * kq + 0], H.x, a1);
            b0 = dot2f(wa[4 * kq + 1], H.y, b0); b1 = dot2f(wb[4 * kq + 1], H.y, b1);
            a0 = dot2f(wa[4 * kq + 2], H.z, a0); a1 = dot2f(wb[4 * kq + 2], H.z, a1);
            b0 = dot2f(wa[4 * kq + 3], H.w, b0); b1 = dot2f(wb[4 * kq + 3], H.w, b1);
        }
#pragma unroll
        for (int kq = 0; kq < KP_LDS / 4; ++kq) {          // 9 iters
            uint4 H  = *(const uint4*)(hp + KP_REG + 4 * kq);
            uint2 w0 = *(const uint2*)(wlds + (4 * kq + 0) * 1024 + j0);
            uint2 w1 = *(const uint2*)(wlds + (4 * kq + 1) * 1024 + j0);
            uint2 w2 = *(const uint2*)(wlds + (4 * kq + 2) * 1024 + j0);
            uint2 w3 = *(const uint2*)(wlds + (4 * kq + 3) * 1024 + j0);
            a0 = dot2f(w0.x, H.x, a0); a1 = dot2f(w0.y, H.x, a1);
            b0 = dot2f(w1.x, H.y, b0); b1 = dot2f(w1.y, H.y, b1);
            a0 = dot2f(w2.x, H.z, a0); a1 = dot2f(w2.y, H.z, a1);
            b0 = dot2f(w3.x, H.w, b0); b1 = dot2f(w3.y, H.w, b1);
        }
        *(float2*)(gs + j0) = make_float2(a0 + b0 + xv.x, a1 + b1 + xv.y);
        __syncthreads();
        if (t < 256) {
            float ig = sigmoidf_(gs[t]);
            float fg = sigmoidf_(gs[256 + t]);
            float gg = tanh_(gs[512 + t]);
            float og = sigmoidf_(gs[768 + t]);
            c = fmaf(fg, c, ig * gg);
            float hn = og * tanh_(c);
            const int tau = d ? (len - 1 - s) : s;
            Hout[(size_t)(b * T_SEQ + tau) * 512 + (d << 8) + t] = f2bf(hn);
            u32 hb = f2h(hn);
            u32 ob = (u32)__shfl_xor((int)hb, 1);
            if (!(t & 1)) hp[t >> 1] = hb | (ob << 16);
            hcur = hn;
        }
        __syncthreads();
    }
    if (t < 256) { st[t] = hcur; st[256 + t] = c; }
}

// ---------------------------------------------------------------------------
// Masked mean-pool over time (bf16 in, fp32 atomically accumulated out).
// grid (32, 8), block 256. pooled must be zeroed first.
// ---------------------------------------------------------------------------
__global__ __launch_bounds__(256) void pooled_kernel(
    const bf16_t* __restrict__ L, const int* __restrict__ lens,
    float* __restrict__ pooled)
{
    const int b     = blockIdx.x;
    const int chunk = blockIdx.y;
    const int tid   = threadIdx.x;
    const int len   = lens[b];
    const int t0    = chunk * 250;
    const int t1    = min(t0 + 250, len);
    const float inv = 1.f / fmaxf((float)len, 1.f);
    float s0 = 0.f, s1 = 0.f;
    for (int t = t0; t < t1; ++t) {
        const bf16_t* row = L + (size_t)(b * T_SEQ + t) * 512;
        s0 += bf2f(row[tid]);
        s1 += bf2f(row[tid + 256]);
    }
    if (t1 > t0) {
        atomicAdd(&pooled[b * 512 + tid], s0 * inv);
        atomicAdd(&pooled[b * 512 + 256 + tid], s1 * inv);
    }
}

// ---------------------------------------------------------------------------
// Utterance head: out[b] = relu(pooled@w1.T + b1) @ w2 + b2.  w1T is (512,512)
// transposed so thread u reads w1T[k*512+u] (coalesced). 32 blocks.
// ---------------------------------------------------------------------------
__global__ __launch_bounds__(256) void utt_head(
    const float* __restrict__ pooled,
    const float* __restrict__ w1T, const float* __restrict__ b1,
    const float* __restrict__ w2, const float* __restrict__ b2,
    float* __restrict__ out)
{
    const int b   = blockIdx.x;
    const int tid = threadIdx.x;
    __shared__ float p[512];
    __shared__ float hid[512];
    __shared__ float red[4];
    p[tid]       = pooled[b * 512 + tid];
    p[tid + 256] = pooled[b * 512 + 256 + tid];
    __syncthreads();
#pragma unroll
    for (int half = 0; half < 2; ++half) {
        int u = tid + half * 256;
        float a = b1[u];
#pragma unroll 8
        for (int k = 0; k < 512; ++k) a = fmaf(w1T[(size_t)k * 512 + u], p[k], a);
        hid[u] = fmaxf(a, 0.f);
    }
    __syncthreads();
    float part = hid[tid] * w2[tid] + hid[tid + 256] * w2[tid + 256];
    for (int off = 32; off; off >>= 1) part += __shfl_down(part, off, 64);
    if ((tid & 63) == 0) red[tid >> 6] = part;
    __syncthreads();
    if (tid == 0) out[b] = red[0] + red[1] + red[2] + red[3] + b2[0];
}

// ---------------------------------------------------------------------------
// Fused segment head: mean over [st,en) of bf16 lstm_out -> relu(W1x+b1) -> w2.
// One block per (b,s); w1T transposed for coalesced reads.
// ---------------------------------------------------------------------------
__global__ __launch_bounds__(256) void seg_head(
    const bf16_t* __restrict__ L, const int* __restrict__ lens,
    const int* __restrict__ segs,
    const float* __restrict__ w1T, const float* __restrict__ b1,
    const float* __restrict__ w2, const float* __restrict__ b2,
    const int* __restrict__ seg_lens, float* __restrict__ out)
{
    const int blk = blockIdx.x;
    const int b   = blk / NSEG;
    const int s   = blk - b * NSEG;
    const int tid = threadIdx.x;
    __shared__ float m[512];
    __shared__ float hid[512];
    __shared__ float red[4];
    const int len = lens[b];
    int st = segs[blk * 2 + 0];
    int en = segs[blk * 2 + 1];
    st = min(max(st, 0), len);
    en = max(st + 1, min(en, len));
    const float inv = 1.f / (float)(en - st);
    float a0 = 0.f, a1 = 0.f;
    for (int t = st; t < en; ++t) {
        const bf16_t* row = L + (size_t)(b * T_SEQ + t) * 512;
        a0 += bf2f(row[tid]);
        a1 += bf2f(row[tid + 256]);
    }
    m[tid]       = a0 * inv;
    m[tid + 256] = a1 * inv;
    __syncthreads();
#pragma unroll
    for (int half = 0; half < 2; ++half) {
        int u = tid + half * 256;
        float a = b1[u];
#pragma unroll 8
        for (int k = 0; k < 512; ++k) a = fmaf(w1T[(size_t)k * 512 + u], m[k], a);
        hid[u] = fmaxf(a, 0.f);
    }
    __syncthreads();
    float part = hid[tid] * w2[tid] + hid[tid + 256] * w2[tid + 256];
    for (int off = 32; off; off >>= 1) part += __shfl_down(part, off, 64);
    if ((tid & 63) == 0) red[tid >> 6] = part;
    __syncthreads();
    if (tid == 0)
        out[BATCH + blk] = (s < seg_lens[b]) ? red[0] + red[1] + red[2] + red[3] + b2[0]
                                             : 0.f;
}

// ---------------------------------------------------------------------------
extern "C" void kernel_launch(void* const* d_in, const int* in_sizes, int n_in,
                              void* d_out, int out_size, void* d_ws, size_t ws_size,
                              hipStream_t stream)
{
    const float* features = (const float*)d_in[0];
    const int*   feat_len = (const int*)d_in[1];
    const int*   segs     = (const int*)d_in[2];
    const int*   seg_lens = (const int*)d_in[3];
    const float* conv1_w  = (const float*)d_in[4];
    const float* conv1_b  = (const float*)d_in[5];
    const float* conv2_w  = (const float*)d_in[6];
    const float* conv2_b  = (const float*)d_in[7];
    const float* wih0     = (const float*)d_in[8];
    const float* whh0     = (const float*)d_in[9];
    const float* bias0    = (const float*)d_in[10];
    const float* wih1     = (const float*)d_in[11];
    const float* whh1     = (const float*)d_in[12];
    const float* bias1    = (const float*)d_in[13];
    const float* seg_w1   = (const float*)d_in[14];
    const float* seg_b1   = (const float*)d_in[15];
    const float* seg_w2   = (const float*)d_in[16];
    const float* seg_b2   = (const float*)d_in[17];
    const float* utt_w1   = (const float*)d_in[18];
    const float* utt_b1   = (const float*)d_in[19];
    const float* utt_w2   = (const float*)d_in[20];
    const float* utt_b2   = (const float*)d_in[21];
    float* out = (float*)d_out;
    char*  wsb = (char*)d_ws;

    // ---- byte-granular workspace plan (256B-aligned regions) ----
    size_t off = 0;
    auto alloc = [&](size_t bytes) -> size_t {
        size_t o = off;
        off += (bytes + 255) & ~(size_t)255;
        return o;
    };
    const size_t o_wt1    = alloc(61440  * 4);            // conv1 w (256,240)
    const size_t o_wt2    = alloc(196608 * 4);            // conv2 w (256,768)
    const size_t o_whh0T  = alloc(524288 * 4);            // (2,256,1024)
    const size_t o_whh1T  = alloc(524288 * 4);
    const size_t o_w16_0  = alloc(262144 * 4);            // (2,128,1024) f16x2
    const size_t o_w16_1  = alloc(262144 * 4);
    const size_t o_sw1T   = alloc(262144 * 4);            // seg w1 transposed
    const size_t o_uw1T   = alloc(262144 * 4);            // utt w1 transposed
    const size_t o_state  = alloc(32768  * 4);            // (64,512) h|c
    const size_t o_pooled = alloc(16384  * 4);
    const size_t o_Hcat   = alloc((size_t)32768000 * 2);  // bf16 (B,T,512)
    const size_t o_lstm   = alloc((size_t)32768000 * 2);  // bf16 (B,T,512)
    // y1 (bf16 B,T,256) and x2 (bf16 B,T,256) alias inside the lstm region:
    // both are dead before the layer-1 recurrence writes lstm_out.
    const size_t o_y1     = o_lstm;
    const size_t o_x2     = o_lstm + (size_t)16384000 * 2;
    const size_t fixed_end = off;

    // ---- pick the largest chunk whose Xp buffers fit ----
    const int cands[] = {250, 200, 125, 100, 50, 40, 25, 20, 10};
    int chunk = 0;
    size_t o_XpF = 0, o_XpB = 0;
    for (int ci = 0; ci < 9; ++ci) {
        int c = cands[ci];
        size_t xp_bytes = ((size_t)c * 32 * 1024 * 4 + 255) & ~(size_t)255;
        if (fixed_end + 2 * xp_bytes <= ws_size) {
            chunk = c;
            o_XpF = fixed_end;
            o_XpB = fixed_end + xp_bytes;
            break;
        }
    }
    if (chunk == 0) {
        ws_guard_kernel<<<(out_size + 255) / 256, 256, 0, stream>>>(out, out_size);
        return;
    }
    const int nph = T_SEQ / chunk;

    float*  wt1    = (float*)(wsb + o_wt1);
    float*  wt2    = (float*)(wsb + o_wt2);
    float*  whh0T  = (float*)(wsb + o_whh0T);
    float*  whh1T  = (float*)(wsb + o_whh1T);
    u32*    w16_0  = (u32*)(wsb + o_w16_0);
    u32*    w16_1  = (u32*)(wsb + o_w16_1);
    float*  sw1T   = (float*)(wsb + o_sw1T);
    float*  uw1T   = (float*)(wsb + o_uw1T);
    float*  state  = (float*)(wsb + o_state);
    float*  pooled = (float*)(wsb + o_pooled);
    bf16_t* Hcat   = (bf16_t*)(wsb + o_Hcat);
    bf16_t* lstm   = (bf16_t*)(wsb + o_lstm);
    bf16_t* y1     = (bf16_t*)(wsb + o_y1);
    bf16_t* x2     = (bf16_t*)(wsb + o_x2);
    float*  XpF    = (float*)(wsb + o_XpF);
    float*  XpB    = (float*)(wsb + o_XpB);

    hipMemsetAsync(state, 0, 32768 * 4, stream);
    hipMemsetAsync(pooled, 0, 16384 * 4, stream);

    // weight re-layouts
    transpose3<<<240, 256, 0, stream>>>(conv1_w, wt1, 256, 80, 3);
    transpose3<<<768, 256, 0, stream>>>(conv2_w, wt2, 256, 256, 3);
    transpose3<<<2048, 256, 0, stream>>>(whh0, whh0T, 2, 1024, 256);
    transpose3<<<2048, 256, 0, stream>>>(whh1, whh1T, 2, 1024, 256);
    transpose3<<<1024, 256, 0, stream>>>(seg_w1, sw1T, 1, 512, 512);
    transpose3<<<1024, 256, 0, stream>>>(utt_w1, uw1T, 1, 512, 512);
    // pack recurrent weights to f16x2 (k-pairs) for on-chip residency
    pack_whh<<<1024, 256, 0, stream>>>(whh0T, w16_0);
    pack_whh<<<1024, 256, 0, stream>>>(whh1T, w16_1);

    // conv1: (B,T,80) -> bf16 (B,T,256), relu
    gemm_nt<1, 80, float, true><<<dim3(250, 4), 256, 0, stream>>>(
        features, wt1, conv1_b, y1, 64000, 256, 240, 1, 0, 0, feat_len);
    // conv2: bf16 (B,T,256) -> bf16 (B,T,256), relu
    gemm_nt<1, 256, bf16_t, true><<<dim3(250, 4), 256, 0, stream>>>(
        y1, wt2, conv2_b, x2, 64000, 256, 768, 1, 0, 0, feat_len);

    const int gx = (32 * chunk + 255) / 256;

    // ---- layer 0: chunked input projection + recurrence ----
    for (int p = 0; p < nph; ++p) {
        const int t0 = p * chunk;
        gemm_nt<2, 1, bf16_t, false><<<dim3(gx, 16), 256, 0, stream>>>(
            x2, wih0, bias0, XpF, 32 * chunk, 1024, 256, 0, t0, chunk, feat_len);
        gemm_nt<3, 1, bf16_t, false><<<dim3(gx, 16), 256, 0, stream>>>(
            x2, wih0 + 1024 * 256, bias0 + 1024, XpB, 32 * chunk, 1024, 256, 0,
            t0, chunk, feat_len);
        lstm_rec_phase<<<64, 512, 0, stream>>>(
            XpF, XpB, w16_0, feat_len, state, Hcat, t0, chunk);
    }

    // reset recurrent state for layer 1
    hipMemsetAsync(state, 0, 32768 * 4, stream);

    // ---- layer 1: chunked input projection + recurrence ----
    for (int p = 0; p < nph; ++p) {
        const int t0 = p * chunk;
        gemm_nt<2, 1, bf16_t, false><<<dim3(gx, 16), 256, 0, stream>>>(
            Hcat, wih1, bias1, XpF, 32 * chunk, 1024, 512, 0, t0, chunk, feat_len);
        gemm_nt<3, 1, bf16_t, false><<<dim3(gx, 16), 256, 0, stream>>>(
            Hcat, wih1 + 1024 * 512, bias1 + 1024, XpB, 32 * chunk, 1024, 512, 0,
            t0, chunk, feat_len);
        lstm_rec_phase<<<64, 512, 0, stream>>>(
            XpF, XpB, w16_1, feat_len, state, lstm, t0, chunk);  // overwrites y1/x2
    }

    // pooled mean + utterance head
    pooled_kernel<<<dim3(32, 8), 256, 0, stream>>>(lstm, feat_len, pooled);
    utt_head<<<32, 256, 0, stream>>>(pooled, uw1T, utt_b1, utt_w2, utt_b2, out);

    // fused segment means + head
    seg_head<<<3200, 256, 0, stream>>>(lstm, feat_len, segs, sw1T, seg_b1,
                                       seg_w2, seg_b2, seg_lens, out);
}

// Round 3
// 14079.208 us; speedup vs baseline: 2.4453x; 1.0176x over previous
//
#include <hip/hip_runtime.h>
#include <math.h>

#define T_SEQ 2000
#define BATCH 32
#define NSEG  100

typedef unsigned short bf16_t;   // raw bf16 storage
typedef unsigned int   u32;
typedef _Float16       half_t;
typedef half_t half2_t __attribute__((ext_vector_type(2)));

// whh f16 split: KP_REG k-pairs live in VGPRs, KP_LDS k-pairs in LDS.
// KP_REG + KP_LDS == 128 (256 k values). KP_REG multiple of 4.
// 2*KP_REG = 192 weight VGPRs/thread; amdgpu_waves_per_eu(2,2) gives the
// allocator a 256-reg budget (LDS caps us at 1 block/CU = 2 waves/EU anyway).
#define KP_REG 96
#define KP_LDS 32

__device__ __forceinline__ float sigmoidf_(float x) {
    return 1.0f / (1.0f + __expf(-x));
}
__device__ __forceinline__ float tanh_(float x) {
    return 1.0f - 2.0f / (__expf(2.0f * x) + 1.0f);
}
__device__ __forceinline__ float bf2f(bf16_t u) {
    return __uint_as_float((unsigned)u << 16);
}
__device__ __forceinline__ bf16_t f2bf(float f) {   // round-to-nearest-even
    unsigned x = __float_as_uint(f);
    return (bf16_t)((x + 0x7FFFu + ((x >> 16) & 1u)) >> 16);
}
// f32 -> f16 bits (RNE via cast)
__device__ __forceinline__ u32 f2h(float f) {
    return (u32)__builtin_bit_cast(unsigned short, (half_t)f);
}
// packed f16x2 dot with f32 accumulate
__device__ __forceinline__ float dot2f(u32 w, u32 h, float acc) {
#if __has_builtin(__builtin_amdgcn_fdot2)
    return __builtin_amdgcn_fdot2(__builtin_bit_cast(half2_t, w),
                                  __builtin_bit_cast(half2_t, h), acc, false);
#else
    half2_t wv = __builtin_bit_cast(half2_t, w);
    half2_t hv = __builtin_bit_cast(half2_t, h);
    acc = fmaf((float)wv.x, (float)hv.x, acc);
    return fmaf((float)wv.y, (float)hv.y, acc);
#endif
}

// 4 consecutive elements -> float4 (fp32 or bf16 source)
__device__ __forceinline__ float4 ld4(const float* p) { return *(const float4*)p; }
__device__ __forceinline__ float4 ld4(const bf16_t* p) {
    ushort4 u = *(const ushort4*)p;
    return make_float4(bf2f(u.x), bf2f(u.y), bf2f(u.z), bf2f(u.w));
}

// ---------------------------------------------------------------------------
// ws too small -> unmistakable signature instead of a fault
// ---------------------------------------------------------------------------
__global__ void ws_guard_kernel(float* out, int n) {
    int i = blockIdx.x * blockDim.x + threadIdx.x;
    if (i < n) out[i] = 1e30f;
}

// ---------------------------------------------------------------------------
// Generic 3D transpose (fp32): in (D0,D1,D2) -> out (D0,D2,D1)
// ---------------------------------------------------------------------------
__global__ void transpose3(const float* __restrict__ in, float* __restrict__ out,
                           int D0, int D1, int D2) {
    int i = blockIdx.x * blockDim.x + threadIdx.x;
    int tot = D0 * D1 * D2;
    if (i >= tot) return;
    int d0 = i / (D1 * D2);
    int r  = i - d0 * (D1 * D2);
    int d1 = r / D2;
    int d2 = r - d1 * D2;
    out[(size_t)d0 * D1 * D2 + (size_t)d2 * D1 + d1] = in[i];
}

// ---------------------------------------------------------------------------
// Pack whhT (2, 256, 1024) f32 -> (2, 128, 1024) u32, each u32 = f16x2 over
// adjacent k (k=2kp low half, k=2kp+1 high half). RNE rounding.
// ---------------------------------------------------------------------------
__global__ __launch_bounds__(256) void pack_whh(const float* __restrict__ whhT,
                                                u32* __restrict__ w16) {
    int i = blockIdx.x * 256 + threadIdx.x;   // 0 .. 262143
    int d  = i >> 17;
    int r  = i & 131071;
    int kp = r >> 10;
    int j  = r & 1023;
    const float* base = whhT + (size_t)d * 262144;
    u32 lo = f2h(base[(size_t)(2 * kp)     * 1024 + j]);
    u32 hi = f2h(base[(size_t)(2 * kp + 1) * 1024 + j]);
    w16[i] = lo | (hi << 16);
}

// ---------------------------------------------------------------------------
// Tiled fp32-compute GEMM:  C[m,n] = sum_k A(row(m))[k]*W[n,k] + bias[n]
// MODE 1: conv im2col  A is (B,T,CIN), k = tap*CIN+c, pad=1
// MODE 2: chunk-fwd    m=(bb,r), A row = bb*T_SEQ + (t0+r)
// MODE 3: chunk-bwd    m=(bb,r), A row = bb*T_SEQ + (lens[bb]-1-(t0+r)); t<0 skip
// TA: float | bf16_t (A storage).  OUT_BF: store C as bf16.
// Tile: 256(M) x 64(N) x 32(K); 256 thr; 8x8 micro-tile.
// LDS pitches 258 / 66 keep LDS ops at <=2-way bank aliasing (free, m136).
// ---------------------------------------------------------------------------
template <int MODE, int CIN, typename TA, bool OUT_BF>
__global__ __launch_bounds__(256) void gemm_nt(
    const TA* __restrict__ A, const float* __restrict__ W,
    const float* __restrict__ bias, void* __restrict__ Cout,
    int M, int N, int K, int relu, int t0, int chunkM,
    const int* __restrict__ lens)
{
    __shared__ float As[32 * 258];
    __shared__ float Ws[32 * 66];
    const int tid    = threadIdx.x;
    const int m_base = blockIdx.x * 256;
    const int n_base = blockIdx.y * 64;
    const int m0     = (tid >> 3) * 8;   // 0..248
    const int n0     = (tid & 7) * 8;    // 0..56
    float acc[8][8] = {};

    for (int k0 = 0; k0 < K; k0 += 32) {
        // ---- stage A tile (256 rows x 32 k), 4 elems per thread-iter ----
#pragma unroll
        for (int i = 0; i < 8; ++i) {
            int f4  = i * 256 + tid;
            int row = f4 >> 3;          // 0..255
            int k4  = (f4 & 7) << 2;    // 0..28
            int gm  = m_base + row;
            int gk  = k0 + k4;
            float4 v = make_float4(0.f, 0.f, 0.f, 0.f);
            if (gm < M && gk < K) {
                if constexpr (MODE == 1) {
                    int bb  = gm / T_SEQ;
                    int tt  = gm - bb * T_SEQ;
                    int tap = gk / CIN;
                    int cc  = gk - tap * CIN;
                    int ts  = tt + tap - 1;
                    if (ts >= 0 && ts < T_SEQ)
                        v = ld4(A + ((size_t)(bb * T_SEQ + ts) * CIN + cc));
                } else {
                    int bb = gm / chunkM;
                    int r  = gm - bb * chunkM;
                    int t  = (MODE == 2) ? (t0 + r) : (lens[bb] - 1 - (t0 + r));
                    if (t >= 0 && t < T_SEQ)
                        v = ld4(A + ((size_t)(bb * T_SEQ + t) * K + gk));
                }
            }
            As[(k4 + 0) * 258 + row] = v.x;
            As[(k4 + 1) * 258 + row] = v.y;
            As[(k4 + 2) * 258 + row] = v.z;
            As[(k4 + 3) * 258 + row] = v.w;
        }
        // ---- stage W tile (64 rows x 32 k) ----
#pragma unroll
        for (int i = 0; i < 2; ++i) {
            int f4  = i * 256 + tid;
            int row = f4 >> 3;          // 0..63
            int k4  = (f4 & 7) << 2;
            int gn  = n_base + row;
            int gk  = k0 + k4;
            float4 v = make_float4(0.f, 0.f, 0.f, 0.f);
            if (gk < K)
                v = *(const float4*)(W + (size_t)gn * K + gk);
            Ws[(k4 + 0) * 66 + row] = v.x;
            Ws[(k4 + 1) * 66 + row] = v.y;
            Ws[(k4 + 2) * 66 + row] = v.z;
            Ws[(k4 + 3) * 66 + row] = v.w;
        }
        __syncthreads();
        // ---- inner product ----
#pragma unroll 8
        for (int kk = 0; kk < 32; ++kk) {
            float am[8], wn[8];
#pragma unroll
            for (int j = 0; j < 4; ++j) {
                float2 a = *(const float2*)(As + kk * 258 + m0 + 2 * j);
                am[2 * j] = a.x; am[2 * j + 1] = a.y;
                float2 w = *(const float2*)(Ws + kk * 66 + n0 + 2 * j);
                wn[2 * j] = w.x; wn[2 * j + 1] = w.y;
            }
#pragma unroll
            for (int im = 0; im < 8; ++im)
#pragma unroll
                for (int in = 0; in < 8; ++in)
                    acc[im][in] = fmaf(am[im], wn[in], acc[im][in]);
        }
        __syncthreads();
    }

    // ---- epilogue: bias (+relu) ----
    float bs[8];
#pragma unroll
    for (int j = 0; j < 8; ++j) bs[j] = bias[n_base + n0 + j];
#pragma unroll
    for (int im = 0; im < 8; ++im) {
        int gm = m_base + m0 + im;
        if (gm < M) {
            float o[8];
#pragma unroll
            for (int j = 0; j < 8; ++j) {
                float v = acc[im][j] + bs[j];
                o[j] = relu ? fmaxf(v, 0.f) : v;
            }
            if constexpr (OUT_BF) {
                bf16_t* crow = (bf16_t*)Cout + (size_t)gm * N + n_base + n0;
                ushort4 u0 = { f2bf(o[0]), f2bf(o[1]), f2bf(o[2]), f2bf(o[3]) };
                ushort4 u1 = { f2bf(o[4]), f2bf(o[5]), f2bf(o[6]), f2bf(o[7]) };
                *(ushort4*)(crow)     = u0;
                *(ushort4*)(crow + 4) = u1;
            } else {
                float* crow = (float*)Cout + (size_t)gm * N + n_base + n0;
                *(float4*)(crow)     = make_float4(o[0], o[1], o[2], o[3]);
                *(float4*)(crow + 4) = make_float4(o[4], o[5], o[6], o[7]);
            }
        }
    }
}

// ---------------------------------------------------------------------------
// LSTM recurrence, one phase of `chunk` steps. One block (512 thr) per (b,dir).
//
// whh is held ON-CHIP for the whole phase as packed f16x2 (k-pairs):
//   kp in [0, KP_REG)          -> VGPRs (uint2/thread -> 192 regs)
//   kp in [KP_REG, 128)        -> LDS   (KP_LDS*1024*4 = 128 KB)
//
// Round 1 compiled at VGPR_Count=128: the allocator targeted 4 waves/EU and
// demoted the weight arrays to scratch (2.7 us/step vs ~0.8 floor).
// amdgpu_waves_per_eu(2,2) pins exactly 2 waves/EU -> 256-reg budget (the
// 132 KB LDS caps us at 1 block/CU = 2 waves/EU anyway). flat_work_group_size
// replaces __launch_bounds__ to avoid emitting a conflicting waves-per-eu.
// (Round 2's per-element asm reg pins are dropped: 192 asm-tied live values
// are a register-allocator pathology risk and unnecessary at a 256 budget.)
//
// Thread t owns gate columns j0=2t, j0+1. Per step:
//   matvec (128 fdot2/col, f32 accum) -> gs[1024] -> barrier ->
//   threads<256: gates -> c,h update -> Hout(bf16) + hp[] (h packed f16x2)
//   -> barrier.
// XpF/XpB: (B, chunk, 1024) fp32 projections (bias included); bwd rows already
// time-reversed. state: (64, 512) fp32 h|c carried across phases.
// Hout: (B, T, 512) bf16; fwd -> [0:256), bwd -> [256:512) at tau.
// ---------------------------------------------------------------------------
__global__
__attribute__((amdgpu_flat_work_group_size(512, 512), amdgpu_waves_per_eu(2, 2)))
void lstm_rec_phase(
    const float* __restrict__ XpF, const float* __restrict__ XpB,
    const u32* __restrict__ whh16, const int* __restrict__ lens,
    float* __restrict__ state, bf16_t* __restrict__ Hout, int s0, int chunk)
{
    __shared__ __align__(16) u32   wlds[KP_LDS * 1024];
    __shared__ __align__(16) float gs[1024];
    __shared__ __align__(16) u32   hp[128];

    const int bd  = blockIdx.x;
    const int b   = bd >> 1;
    const int d   = bd & 1;
    const int t   = threadIdx.x;      // 0..511
    const int j0  = t * 2;
    const int len = lens[b];
    const int s1  = min(s0 + chunk, len);
    const u32* Wg = whh16 + (size_t)d * (128 * 1024);

    // ---- load whh f16x2: registers (kp < KP_REG) + LDS (rest) ----
    uint2 w2[KP_REG];                 // .x: col j0, .y: col j0+1
#pragma unroll
    for (int kp = 0; kp < KP_REG; ++kp)
        w2[kp] = *(const uint2*)(Wg + (size_t)kp * 1024 + j0);
#pragma unroll 4
    for (int kpl = 0; kpl < KP_LDS; ++kpl)
        *(uint2*)(wlds + kpl * 1024 + j0) =
            *(const uint2*)(Wg + (size_t)(KP_REG + kpl) * 1024 + j0);

    // ---- init state + packed h ----
    float* st = state + bd * 512;
    float c = 0.f, hcur = 0.f;
    if (t < 256) {
        if (s0 > 0) { hcur = st[t]; c = st[256 + t]; }
        u32 hb = f2h(hcur);
        u32 ob = (u32)__shfl_xor((int)hb, 1);
        if (!(t & 1)) hp[t >> 1] = hb | (ob << 16);
    }
    __syncthreads();

    const float* xrow = ((d ? XpB : XpF) + (size_t)b * ((size_t)chunk * 1024));
    for (int s = s0; s < s1; ++s, xrow += 1024) {
        float2 xv = *(const float2*)(xrow + j0);   // issued early, used late
        float a0 = 0.f, a1 = 0.f, b0 = 0.f, b1 = 0.f;
#pragma unroll
        for (int kq = 0; kq < KP_REG / 4; ++kq) {          // 24 iters
            uint4 H = *(const uint4*)(hp + 4 * kq);
            a0 = dot2f(w2[4 * kq + 0].x, H.x, a0); a1 = dot2f(w2[4 * kq + 0].y, H.x, a1);
            b0 = dot2f(w2[4 * kq + 1].x, H.y, b0); b1 = dot2f(w2[4 * kq + 1].y, H.y, b1);
            a0 = dot2f(w2[4 * kq + 2].x, H.z, a0); a1 = dot2f(w2[4 * kq + 2].y, H.z, a1);
            b0 = dot2f(w2[4 * kq + 3].x, H.w, b0); b1 = dot2f(w2[4 * kq + 3].y, H.w, b1);
        }
#pragma unroll
        for (int kq = 0; kq < KP_LDS / 4; ++kq) {          // 8 iters
            uint4 H  = *(const uint4*)(hp + KP_REG + 4 * kq);
            uint2 w0 = *(const uint2*)(wlds + (4 * kq + 0) * 1024 + j0);
            uint2 w1 = *(const uint2*)(wlds + (4 * kq + 1) * 1024 + j0);
            uint2 wv2 = *(const uint2*)(wlds + (4 * kq + 2) * 1024 + j0);
            uint2 wv3 = *(const uint2*)(wlds + (4 * kq + 3) * 1024 + j0);
            a0 = dot2f(w0.x, H.x, a0);  a1 = dot2f(w0.y, H.x, a1);
            b0 = dot2f(w1.x, H.y, b0);  b1 = dot2f(w1.y, H.y, b1);
            a0 = dot2f(wv2.x, H.z, a0); a1 = dot2f(wv2.y, H.z, a1);
            b0 = dot2f(wv3.x, H.w, b0); b1 = dot2f(wv3.y, H.w, b1);
        }
        *(float2*)(gs + j0) = make_float2(a0 + b0 + xv.x, a1 + b1 + xv.y);
        __syncthreads();
        if (t < 256) {
            float ig = sigmoidf_(gs[t]);
            float fg = sigmoidf_(gs[256 + t]);
            float gg = tanh_(gs[512 + t]);
            float og = sigmoidf_(gs[768 + t]);
            c = fmaf(fg, c, ig * gg);
            float hn = og * tanh_(c);
            const int tau = d ? (len - 1 - s) : s;
            Hout[(size_t)(b * T_SEQ + tau) * 512 + (d << 8) + t] = f2bf(hn);
            u32 hb = f2h(hn);
            u32 ob = (u32)__shfl_xor((int)hb, 1);
            if (!(t & 1)) hp[t >> 1] = hb | (ob << 16);
            hcur = hn;
        }
        __syncthreads();
    }
    if (t < 256) { st[t] = hcur; st[256 + t] = c; }
}

// ---------------------------------------------------------------------------
// Masked mean-pool over time (bf16 in, fp32 atomically accumulated out).
// grid (32, 8), block 256. pooled must be zeroed first.
// ---------------------------------------------------------------------------
__global__ __launch_bounds__(256) void pooled_kernel(
    const bf16_t* __restrict__ L, const int* __restrict__ lens,
    float* __restrict__ pooled)
{
    const int b     = blockIdx.x;
    const int chunk = blockIdx.y;
    const int tid   = threadIdx.x;
    const int len   = lens[b];
    const int t0    = chunk * 250;
    const int t1    = min(t0 + 250, len);
    const float inv = 1.f / fmaxf((float)len, 1.f);
    float s0 = 0.f, s1 = 0.f;
    for (int t = t0; t < t1; ++t) {
        const bf16_t* row = L + (size_t)(b * T_SEQ + t) * 512;
        s0 += bf2f(row[tid]);
        s1 += bf2f(row[tid + 256]);
    }
    if (t1 > t0) {
        atomicAdd(&pooled[b * 512 + tid], s0 * inv);
        atomicAdd(&pooled[b * 512 + 256 + tid], s1 * inv);
    }
}

// ---------------------------------------------------------------------------
// Utterance head: out[b] = relu(pooled@w1.T + b1) @ w2 + b2.  w1T is (512,512)
// transposed so thread u reads w1T[k*512+u] (coalesced). 32 blocks.
// ---------------------------------------------------------------------------
__global__ __launch_bounds__(256) void utt_head(
    const float* __restrict__ pooled,
    const float* __restrict__ w1T, const float* __restrict__ b1,
    const float* __restrict__ w2, const float* __restrict__ b2,
    float* __restrict__ out)
{
    const int b   = blockIdx.x;
    const int tid = threadIdx.x;
    __shared__ float p[512];
    __shared__ float hid[512];
    __shared__ float red[4];
    p[tid]       = pooled[b * 512 + tid];
    p[tid + 256] = pooled[b * 512 + 256 + tid];
    __syncthreads();
#pragma unroll
    for (int half = 0; half < 2; ++half) {
        int u = tid + half * 256;
        float a = b1[u];
#pragma unroll 8
        for (int k = 0; k < 512; ++k) a = fmaf(w1T[(size_t)k * 512 + u], p[k], a);
        hid[u] = fmaxf(a, 0.f);
    }
    __syncthreads();
    float part = hid[tid] * w2[tid] + hid[tid + 256] * w2[tid + 256];
    for (int off = 32; off; off >>= 1) part += __shfl_down(part, off, 64);
    if ((tid & 63) == 0) red[tid >> 6] = part;
    __syncthreads();
    if (tid == 0) out[b] = red[0] + red[1] + red[2] + red[3] + b2[0];
}

// ---------------------------------------------------------------------------
// Fused segment head: mean over [st,en) of bf16 lstm_out -> relu(W1x+b1) -> w2.
// One block per (b,s); w1T transposed for coalesced reads.
// ---------------------------------------------------------------------------
__global__ __launch_bounds__(256) void seg_head(
    const bf16_t* __restrict__ L, const int* __restrict__ lens,
    const int* __restrict__ segs,
    const float* __restrict__ w1T, const float* __restrict__ b1,
    const float* __restrict__ w2, const float* __restrict__ b2,
    const int* __restrict__ seg_lens, float* __restrict__ out)
{
    const int blk = blockIdx.x;
    const int b   = blk / NSEG;
    const int s   = blk - b * NSEG;
    const int tid = threadIdx.x;
    __shared__ float m[512];
    __shared__ float hid[512];
    __shared__ float red[4];
    const int len = lens[b];
    int st = segs[blk * 2 + 0];
    int en = segs[blk * 2 + 1];
    st = min(max(st, 0), len);
    en = max(st + 1, min(en, len));
    const float inv = 1.f / (float)(en - st);
    float a0 = 0.f, a1 = 0.f;
    for (int t = st; t < en; ++t) {
        const bf16_t* row = L + (size_t)(b * T_SEQ + t) * 512;
        a0 += bf2f(row[tid]);
        a1 += bf2f(row[tid + 256]);
    }
    m[tid]       = a0 * inv;
    m[tid + 256] = a1 * inv;
    __syncthreads();
#pragma unroll
    for (int half = 0; half < 2; ++half) {
        int u = tid + half * 256;
        float a = b1[u];
#pragma unroll 8
        for (int k = 0; k < 512; ++k) a = fmaf(w1T[(size_t)k * 512 + u], m[k], a);
        hid[u] = fmaxf(a, 0.f);
    }
    __syncthreads();
    float part = hid[tid] * w2[tid] + hid[tid + 256] * w2[tid + 256];
    for (int off = 32; off; off >>= 1) part += __shfl_down(part, off, 64);
    if ((tid & 63) == 0) red[tid >> 6] = part;
    __syncthreads();
    if (tid == 0)
        out[BATCH + blk] = (s < seg_lens[b]) ? red[0] + red[1] + red[2] + red[3] + b2[0]
                                             : 0.f;
}

// ---------------------------------------------------------------------------
extern "C" void kernel_launch(void* const* d_in, const int* in_sizes, int n_in,
                              void* d_out, int out_size, void* d_ws, size_t ws_size,
                              hipStream_t stream)
{
    const float* features = (const float*)d_in[0];
    const int*   feat_len = (const int*)d_in[1];
    const int*   segs     = (const int*)d_in[2];
    const int*   seg_lens = (const int*)d_in[3];
    const float* conv1_w  = (const float*)d_in[4];
    const float* conv1_b  = (const float*)d_in[5];
    const float* conv2_w  = (const float*)d_in[6];
    const float* conv2_b  = (const float*)d_in[7];
    const float* wih0     = (const float*)d_in[8];
    const float* whh0     = (const float*)d_in[9];
    const float* bias0    = (const float*)d_in[10];
    const float* wih1     = (const float*)d_in[11];
    const float* whh1     = (const float*)d_in[12];
    const float* bias1    = (const float*)d_in[13];
    const float* seg_w1   = (const float*)d_in[14];
    const float* seg_b1   = (const float*)d_in[15];
    const float* seg_w2   = (const float*)d_in[16];
    const float* seg_b2   = (const float*)d_in[17];
    const float* utt_w1   = (const float*)d_in[18];
    const float* utt_b1   = (const float*)d_in[19];
    const float* utt_w2   = (const float*)d_in[20];
    const float* utt_b2   = (const float*)d_in[21];
    float* out = (float*)d_out;
    char*  wsb = (char*)d_ws;

    // ---- byte-granular workspace plan (256B-aligned regions) ----
    size_t off = 0;
    auto alloc = [&](size_t bytes) -> size_t {
        size_t o = off;
        off += (bytes + 255) & ~(size_t)255;
        return o;
    };
    const size_t o_wt1    = alloc(61440  * 4);            // conv1 w (256,240)
    const size_t o_wt2    = alloc(196608 * 4);            // conv2 w (256,768)
    const size_t o_whh0T  = alloc(524288 * 4);            // (2,256,1024)
    const size_t o_whh1T  = alloc(524288 * 4);
    const size_t o_w16_0  = alloc(262144 * 4);            // (2,128,1024) f16x2
    const size_t o_w16_1  = alloc(262144 * 4);
    const size_t o_sw1T   = alloc(262144 * 4);            // seg w1 transposed
    const size_t o_uw1T   = alloc(262144 * 4);            // utt w1 transposed
    const size_t o_state  = alloc(32768  * 4);            // (64,512) h|c
    const size_t o_pooled = alloc(16384  * 4);
    const size_t o_Hcat   = alloc((size_t)32768000 * 2);  // bf16 (B,T,512)
    const size_t o_lstm   = alloc((size_t)32768000 * 2);  // bf16 (B,T,512)
    // y1 (bf16 B,T,256) and x2 (bf16 B,T,256) alias inside the lstm region:
    // both are dead before the layer-1 recurrence writes lstm_out.
    const size_t o_y1     = o_lstm;
    const size_t o_x2     = o_lstm + (size_t)16384000 * 2;
    const size_t fixed_end = off;

    // ---- pick the largest chunk whose Xp buffers fit ----
    const int cands[] = {250, 200, 125, 100, 50, 40, 25, 20, 10};
    int chunk = 0;
    size_t o_XpF = 0, o_XpB = 0;
    for (int ci = 0; ci < 9; ++ci) {
        int c = cands[ci];
        size_t xp_bytes = ((size_t)c * 32 * 1024 * 4 + 255) & ~(size_t)255;
        if (fixed_end + 2 * xp_bytes <= ws_size) {
            chunk = c;
            o_XpF = fixed_end;
            o_XpB = fixed_end + xp_bytes;
            break;
        }
    }
    if (chunk == 0) {
        ws_guard_kernel<<<(out_size + 255) / 256, 256, 0, stream>>>(out, out_size);
        return;
    }
    const int nph = T_SEQ / chunk;

    float*  wt1    = (float*)(wsb + o_wt1);
    float*  wt2    = (float*)(wsb + o_wt2);
    float*  whh0T  = (float*)(wsb + o_whh0T);
    float*  whh1T  = (float*)(wsb + o_whh1T);
    u32*    w16_0  = (u32*)(wsb + o_w16_0);
    u32*    w16_1  = (u32*)(wsb + o_w16_1);
    float*  sw1T   = (float*)(wsb + o_sw1T);
    float*  uw1T   = (float*)(wsb + o_uw1T);
    float*  state  = (float*)(wsb + o_state);
    float*  pooled = (float*)(wsb + o_pooled);
    bf16_t* Hcat   = (bf16_t*)(wsb + o_Hcat);
    bf16_t* lstm   = (bf16_t*)(wsb + o_lstm);
    bf16_t* y1     = (bf16_t*)(wsb + o_y1);
    bf16_t* x2     = (bf16_t*)(wsb + o_x2);
    float*  XpF    = (float*)(wsb + o_XpF);
    float*  XpB    = (float*)(wsb + o_XpB);

    hipMemsetAsync(state, 0, 32768 * 4, stream);
    hipMemsetAsync(pooled, 0, 16384 * 4, stream);

    // weight re-layouts
    transpose3<<<240, 256, 0, stream>>>(conv1_w, wt1, 256, 80, 3);
    transpose3<<<768, 256, 0, stream>>>(conv2_w, wt2, 256, 256, 3);
    transpose3<<<2048, 256, 0, stream>>>(whh0, whh0T, 2, 1024, 256);
    transpose3<<<2048, 256, 0, stream>>>(whh1, whh1T, 2, 1024, 256);
    transpose3<<<1024, 256, 0, stream>>>(seg_w1, sw1T, 1, 512, 512);
    transpose3<<<1024, 256, 0, stream>>>(utt_w1, uw1T, 1, 512, 512);
    // pack recurrent weights to f16x2 (k-pairs) for on-chip residency
    pack_whh<<<1024, 256, 0, stream>>>(whh0T, w16_0);
    pack_whh<<<1024, 256, 0, stream>>>(whh1T, w16_1);

    // conv1: (B,T,80) -> bf16 (B,T,256), relu
    gemm_nt<1, 80, float, true><<<dim3(250, 4), 256, 0, stream>>>(
        features, wt1, conv1_b, y1, 64000, 256, 240, 1, 0, 0, feat_len);
    // conv2: bf16 (B,T,256) -> bf16 (B,T,256), relu
    gemm_nt<1, 256, bf16_t, true><<<dim3(250, 4), 256, 0, stream>>>(
        y1, wt2, conv2_b, x2, 64000, 256, 768, 1, 0, 0, feat_len);

    const int gx = (32 * chunk + 255) / 256;

    // ---- layer 0: chunked input projection + recurrence ----
    for (int p = 0; p < nph; ++p) {
        const int t0 = p * chunk;
        gemm_nt<2, 1, bf16_t, false><<<dim3(gx, 16), 256, 0, stream>>>(
            x2, wih0, bias0, XpF, 32 * chunk, 1024, 256, 0, t0, chunk, feat_len);
        gemm_nt<3, 1, bf16_t, false><<<dim3(gx, 16), 256, 0, stream>>>(
            x2, wih0 + 1024 * 256, bias0 + 1024, XpB, 32 * chunk, 1024, 256, 0,
            t0, chunk, feat_len);
        lstm_rec_phase<<<64, 512, 0, stream>>>(
            XpF, XpB, w16_0, feat_len, state, Hcat, t0, chunk);
    }

    // reset recurrent state for layer 1
    hipMemsetAsync(state, 0, 32768 * 4, stream);

    // ---- layer 1: chunked input projection + recurrence ----
    for (int p = 0; p < nph; ++p) {
        const int t0 = p * chunk;
        gemm_nt<2, 1, bf16_t, false><<<dim3(gx, 16), 256, 0, stream>>>(
            Hcat, wih1, bias1, XpF, 32 * chunk, 1024, 512, 0, t0, chunk, feat_len);
        gemm_nt<3, 1, bf16_t, false><<<dim3(gx, 16), 256, 0, stream>>>(
            Hcat, wih1 + 1024 * 512, bias1 + 1024, XpB, 32 * chunk, 1024, 512, 0,
            t0, chunk, feat_len);
        lstm_rec_phase<<<64, 512, 0, stream>>>(
            XpF, XpB, w16_1, feat_len, state, lstm, t0, chunk);  // overwrites y1/x2
    }

    // pooled mean + utterance head
    pooled_kernel<<<dim3(32, 8), 256, 0, stream>>>(lstm, feat_len, pooled);
    utt_head<<<32, 256, 0, stream>>>(pooled, uw1T, utt_b1, utt_w2, utt_b2, out);

    // fused segment means + head
    seg_head<<<3200, 256, 0, stream>>>(lstm, feat_len, segs, sw1T, seg_b1,
                                       seg_w2, seg_b2, seg_lens, out);
}

// Round 4
// 11331.746 us; speedup vs baseline: 3.0382x; 1.2425x over previous
//
#include <hip/hip_runtime.h>
#include <math.h>

#define T_SEQ 2000
#define BATCH 32
#define NSEG  100

typedef unsigned short bf16_t;   // raw bf16 storage
typedef unsigned int   u32;
typedef _Float16       half_t;
typedef half_t half2_t __attribute__((ext_vector_type(2)));

// whh f16 split: KP_REG k-pairs live in VGPRs/AGPRs, KP_LDS k-pairs in LDS.
// KP_REG + KP_LDS == 128 (256 k values).
#define KP_REG 96
#define KP_LDS 32
#define NG     (KP_LDS / 4)        // 8 b128-groups per column

__device__ __forceinline__ float sigmoidf_(float x) {
    return 1.0f / (1.0f + __expf(-x));
}
__device__ __forceinline__ float tanh_(float x) {
    return 1.0f - 2.0f / (__expf(2.0f * x) + 1.0f);
}
__device__ __forceinline__ float bf2f(bf16_t u) {
    return __uint_as_float((unsigned)u << 16);
}
__device__ __forceinline__ bf16_t f2bf(float f) {   // round-to-nearest-even
    unsigned x = __float_as_uint(f);
    return (bf16_t)((x + 0x7FFFu + ((x >> 16) & 1u)) >> 16);
}
// f32 -> f16 bits (RNE via cast)
__device__ __forceinline__ u32 f2h(float f) {
    return (u32)__builtin_bit_cast(unsigned short, (half_t)f);
}
// packed f16x2 dot with f32 accumulate
__device__ __forceinline__ float dot2f(u32 w, u32 h, float acc) {
    return __builtin_amdgcn_fdot2(__builtin_bit_cast(half2_t, w),
                                  __builtin_bit_cast(half2_t, h), acc, false);
}
// broadcast lane's u32 to all lanes (lands in SGPR; fdot2 takes it as scalar)
__device__ __forceinline__ u32 rl(u32 v, int l) {
    return (u32)__builtin_amdgcn_readlane((int)v, l);
}

// 4 consecutive elements -> float4 (fp32 or bf16 source)
__device__ __forceinline__ float4 ld4(const float* p) { return *(const float4*)p; }
__device__ __forceinline__ float4 ld4(const bf16_t* p) {
    ushort4 u = *(const ushort4*)p;
    return make_float4(bf2f(u.x), bf2f(u.y), bf2f(u.z), bf2f(u.w));
}

// ---------------------------------------------------------------------------
// ws too small -> unmistakable signature instead of a fault
// ---------------------------------------------------------------------------
__global__ void ws_guard_kernel(float* out, int n) {
    int i = blockIdx.x * blockDim.x + threadIdx.x;
    if (i < n) out[i] = 1e30f;
}

// ---------------------------------------------------------------------------
// Generic 3D transpose (fp32): in (D0,D1,D2) -> out (D0,D2,D1)
// ---------------------------------------------------------------------------
__global__ void transpose3(const float* __restrict__ in, float* __restrict__ out,
                           int D0, int D1, int D2) {
    int i = blockIdx.x * blockDim.x + threadIdx.x;
    int tot = D0 * D1 * D2;
    if (i >= tot) return;
    int d0 = i / (D1 * D2);
    int r  = i - d0 * (D1 * D2);
    int d1 = r / D2;
    int d2 = r - d1 * D2;
    out[(size_t)d0 * D1 * D2 + (size_t)d2 * D1 + d1] = in[i];
}

// ---------------------------------------------------------------------------
// Pack whhT (2, 256, 1024) f32 ->
//  w16: (2, 128, 1024) u32, u32 = f16x2 over adjacent k  (VGPR-portion loads)
//  wp4: (2, 2, NG, 512) uint4 for the LDS portion (kp >= KP_REG):
//       wp4[d][j&1][g][j>>1].c = f16x2 w[2(KP_REG+4g+c)..+1][j]
//       -> per-thread b128 reads at 16B lane stride (bank-optimal).
// ---------------------------------------------------------------------------
__global__ __launch_bounds__(256) void pack_whh(const float* __restrict__ whhT,
                                                u32* __restrict__ w16,
                                                u32* __restrict__ wp4) {
    int i = blockIdx.x * 256 + threadIdx.x;   // 0 .. 262143
    int d  = i >> 17;
    int r  = i & 131071;
    int kp = r >> 10;
    int j  = r & 1023;
    const float* base = whhT + (size_t)d * 262144;
    u32 lo = f2h(base[(size_t)(2 * kp)     * 1024 + j]);
    u32 hi = f2h(base[(size_t)(2 * kp + 1) * 1024 + j]);
    u32 val = lo | (hi << 16);
    w16[i] = val;
    if (kp >= KP_REG) {
        int g  = (kp - KP_REG) >> 2;
        int cc = (kp - KP_REG) & 3;
        size_t idx = ((((size_t)d * 2 + (j & 1)) * NG + g) * 512 + (j >> 1)) * 4 + cc;
        wp4[idx] = val;
    }
}

// ---------------------------------------------------------------------------
// Tiled fp32-compute GEMM:  C[m,n] = sum_k A(row(m))[k]*W[n,k] + bias[n]
// MODE 1: conv im2col  A is (B,T,CIN), k = tap*CIN+c, pad=1
// MODE 2: chunk-fwd    m=(bb,r), A row = bb*T_SEQ + (t0+r)
// MODE 3: chunk-bwd    m=(bb,r), A row = bb*T_SEQ + (lens[bb]-1-(t0+r)); t<0 skip
// TA: float | bf16_t (A storage).  OUT_BF: store C as bf16.
// Tile: 256(M) x 64(N) x 32(K); 256 thr; 8x8 micro-tile.
// ---------------------------------------------------------------------------
template <int MODE, int CIN, typename TA, bool OUT_BF>
__global__ __launch_bounds__(256) void gemm_nt(
    const TA* __restrict__ A, const float* __restrict__ W,
    const float* __restrict__ bias, void* __restrict__ Cout,
    int M, int N, int K, int relu, int t0, int chunkM,
    const int* __restrict__ lens)
{
    __shared__ float As[32 * 258];
    __shared__ float Ws[32 * 66];
    const int tid    = threadIdx.x;
    const int m_base = blockIdx.x * 256;
    const int n_base = blockIdx.y * 64;
    const int m0     = (tid >> 3) * 8;   // 0..248
    const int n0     = (tid & 7) * 8;    // 0..56
    float acc[8][8] = {};

    for (int k0 = 0; k0 < K; k0 += 32) {
        // ---- stage A tile (256 rows x 32 k), 4 elems per thread-iter ----
#pragma unroll
        for (int i = 0; i < 8; ++i) {
            int f4  = i * 256 + tid;
            int row = f4 >> 3;          // 0..255
            int k4  = (f4 & 7) << 2;    // 0..28
            int gm  = m_base + row;
            int gk  = k0 + k4;
            float4 v = make_float4(0.f, 0.f, 0.f, 0.f);
            if (gm < M && gk < K) {
                if constexpr (MODE == 1) {
                    int bb  = gm / T_SEQ;
                    int tt  = gm - bb * T_SEQ;
                    int tap = gk / CIN;
                    int cc  = gk - tap * CIN;
                    int ts  = tt + tap - 1;
                    if (ts >= 0 && ts < T_SEQ)
                        v = ld4(A + ((size_t)(bb * T_SEQ + ts) * CIN + cc));
                } else {
                    int bb = gm / chunkM;
                    int r  = gm - bb * chunkM;
                    int t  = (MODE == 2) ? (t0 + r) : (lens[bb] - 1 - (t0 + r));
                    if (t >= 0 && t < T_SEQ)
                        v = ld4(A + ((size_t)(bb * T_SEQ + t) * K + gk));
                }
            }
            As[(k4 + 0) * 258 + row] = v.x;
            As[(k4 + 1) * 258 + row] = v.y;
            As[(k4 + 2) * 258 + row] = v.z;
            As[(k4 + 3) * 258 + row] = v.w;
        }
        // ---- stage W tile (64 rows x 32 k) ----
#pragma unroll
        for (int i = 0; i < 2; ++i) {
            int f4  = i * 256 + tid;
            int row = f4 >> 3;          // 0..63
            int k4  = (f4 & 7) << 2;
            int gn  = n_base + row;
            int gk  = k0 + k4;
            float4 v = make_float4(0.f, 0.f, 0.f, 0.f);
            if (gk < K)
                v = *(const float4*)(W + (size_t)gn * K + gk);
            Ws[(k4 + 0) * 66 + row] = v.x;
            Ws[(k4 + 1) * 66 + row] = v.y;
            Ws[(k4 + 2) * 66 + row] = v.z;
            Ws[(k4 + 3) * 66 + row] = v.w;
        }
        __syncthreads();
        // ---- inner product ----
#pragma unroll 8
        for (int kk = 0; kk < 32; ++kk) {
            float am[8], wn[8];
#pragma unroll
            for (int j = 0; j < 4; ++j) {
                float2 a = *(const float2*)(As + kk * 258 + m0 + 2 * j);
                am[2 * j] = a.x; am[2 * j + 1] = a.y;
                float2 w = *(const float2*)(Ws + kk * 66 + n0 + 2 * j);
                wn[2 * j] = w.x; wn[2 * j + 1] = w.y;
            }
#pragma unroll
            for (int im = 0; im < 8; ++im)
#pragma unroll
                for (int in = 0; in < 8; ++in)
                    acc[im][in] = fmaf(am[im], wn[in], acc[im][in]);
        }
        __syncthreads();
    }

    // ---- epilogue: bias (+relu) ----
    float bs[8];
#pragma unroll
    for (int j = 0; j < 8; ++j) bs[j] = bias[n_base + n0 + j];
#pragma unroll
    for (int im = 0; im < 8; ++im) {
        int gm = m_base + m0 + im;
        if (gm < M) {
            float o[8];
#pragma unroll
            for (int j = 0; j < 8; ++j) {
                float v = acc[im][j] + bs[j];
                o[j] = relu ? fmaxf(v, 0.f) : v;
            }
            if constexpr (OUT_BF) {
                bf16_t* crow = (bf16_t*)Cout + (size_t)gm * N + n_base + n0;
                ushort4 u0 = { f2bf(o[0]), f2bf(o[1]), f2bf(o[2]), f2bf(o[3]) };
                ushort4 u1 = { f2bf(o[4]), f2bf(o[5]), f2bf(o[6]), f2bf(o[7]) };
                *(ushort4*)(crow)     = u0;
                *(ushort4*)(crow + 4) = u1;
            } else {
                float* crow = (float*)Cout + (size_t)gm * N + n_base + n0;
                *(float4*)(crow)     = make_float4(o[0], o[1], o[2], o[3]);
                *(float4*)(crow + 4) = make_float4(o[4], o[5], o[6], o[7]);
            }
        }
    }
}

// ---------------------------------------------------------------------------
// LSTM recurrence, one phase of `chunk` steps. One block (512 thr) per (b,dir).
//
// whh on-chip for the whole phase: kp<KP_REG in registers (192 dwords/thread),
// kp>=KP_REG in LDS (128 KB, b128-packed per column pair).
//
// ROUND-4 FIX (LDS-broadcast bound, r3 counters): the old per-step hp read
// (32 ds_read_b128/thread, 64x broadcast amplification) was ~4900 cyc/CU/step
// — the measured 2.6 us/step. Now each lane loads only ITS 8 B of h
// (1 ds_read_b64) and the matvec broadcasts h via v_readlane -> SGPR, which
// v_dot2_f32_f16 consumes as its one scalar operand. LDS-weight reads are
// b128-packed at 16 B lane stride (bank-optimal). Per-step LDS drops
// ~4900 -> ~1150 cyc; VALU becomes the limiter (~1700 cyc).
//
// Thread t owns gate columns j0=2t, j0+1. Per step:
//   matvec -> gs[1024] -> barrier -> threads<256: gates -> c,h ->
//   Hout(bf16) + hp[] (h packed f16x2) -> barrier.
// XpF/XpB: (B, chunk, 1024) fp32 projections (bias included); bwd rows already
// time-reversed. state: (64, 512) fp32 h|c carried across phases.
// Hout: (B, T, 512) bf16; fwd -> [0:256), bwd -> [256:512) at tau.
// ---------------------------------------------------------------------------
__global__
__attribute__((amdgpu_flat_work_group_size(512, 512), amdgpu_waves_per_eu(2, 2)))
void lstm_rec_phase(
    const float* __restrict__ XpF, const float* __restrict__ XpB,
    const u32* __restrict__ whh16, const uint4* __restrict__ wp4,
    const int* __restrict__ lens,
    float* __restrict__ state, bf16_t* __restrict__ Hout, int s0, int chunk)
{
    __shared__ __align__(16) uint4 wlds4[2 * NG * 512];   // 128 KB
    __shared__ __align__(16) float gs[1024];
    __shared__ __align__(16) u32   hp[128];

    const int bd   = blockIdx.x;
    const int b    = bd >> 1;
    const int d    = bd & 1;
    const int t    = threadIdx.x;      // 0..511
    const int j0   = t * 2;
    const int lane = t & 63;
    const int len  = lens[b];
    const int s1   = min(s0 + chunk, len);
    const u32*   Wg = whh16 + (size_t)d * (128 * 1024);
    const uint4* Wp = wp4   + (size_t)d * (2 * NG * 512);

    // ---- load whh f16x2: registers (kp < KP_REG) + LDS (rest, b128-packed) --
    uint2 w2[KP_REG];                 // .x: col j0, .y: col j0+1
#pragma unroll
    for (int kp = 0; kp < KP_REG; ++kp)
        w2[kp] = *(const uint2*)(Wg + (size_t)kp * 1024 + j0);
#pragma unroll
    for (int i = 0; i < 2 * NG; ++i)
        wlds4[i * 512 + t] = Wp[i * 512 + t];

    // ---- init state + packed h ----
    float* st = state + bd * 512;
    float c = 0.f, hcur = 0.f;
    if (t < 256) {
        if (s0 > 0) { hcur = st[t]; c = st[256 + t]; }
        u32 hb = f2h(hcur);
        u32 ob = (u32)__shfl_xor((int)hb, 1);
        if (!(t & 1)) hp[t >> 1] = hb | (ob << 16);
    }
    __syncthreads();

    const float* xrow = ((d ? XpB : XpF) + (size_t)b * ((size_t)chunk * 1024));
    const uint4* wpA = wlds4 + t;                 // col j0 groups
    const uint4* wpB = wlds4 + NG * 512 + t;      // col j0+1 groups
    for (int s = s0; s < s1; ++s, xrow += 1024) {
        float2 xv = *(const float2*)(xrow + j0);          // early issue
        uint2 hreg = *(const uint2*)(hp + 2 * lane);      // own 8B of h
        float a0 = 0.f, a1 = 0.f, b0 = 0.f, b1 = 0.f;
#pragma unroll
        for (int kp = 0; kp < KP_REG; kp += 2) {          // 48 iters
            u32 h0 = rl(hreg.x, kp >> 1);                 // hp[kp]
            u32 h1 = rl(hreg.y, kp >> 1);                 // hp[kp+1]
            a0 = dot2f(w2[kp].x,     h0, a0); a1 = dot2f(w2[kp].y,     h0, a1);
            b0 = dot2f(w2[kp + 1].x, h1, b0); b1 = dot2f(w2[kp + 1].y, h1, b1);
        }
#pragma unroll
        for (int g = 0; g < NG; ++g) {                    // 8 iters
            uint4 wA = wpA[g * 512];
            uint4 wB = wpB[g * 512];
            const int lb = (KP_REG >> 1) + 2 * g;         // base lane for hp
            u32 h0 = rl(hreg.x, lb);                      // hp[KP_REG+4g]
            u32 h1 = rl(hreg.y, lb);                      // +1
            u32 h2 = rl(hreg.x, lb + 1);                  // +2
            u32 h3 = rl(hreg.y, lb + 1);                  // +3
            a0 = dot2f(wA.x, h0, a0); a1 = dot2f(wB.x, h0, a1);
            b0 = dot2f(wA.y, h1, b0); b1 = dot2f(wB.y, h1, b1);
            a0 = dot2f(wA.z, h2, a0); a1 = dot2f(wB.z, h2, a1);
            b0 = dot2f(wA.w, h3, b0); b1 = dot2f(wB.w, h3, b1);
        }
        *(float2*)(gs + j0) = make_float2(a0 + b0 + xv.x, a1 + b1 + xv.y);
        __syncthreads();
        if (t < 256) {
            float ig = sigmoidf_(gs[t]);
            float fg = sigmoidf_(gs[256 + t]);
            float gg = tanh_(gs[512 + t]);
            float og = sigmoidf_(gs[768 + t]);
            c = fmaf(fg, c, ig * gg);
            float hn = og * tanh_(c);
            const int tau = d ? (len - 1 - s) : s;
            Hout[(size_t)(b * T_SEQ + tau) * 512 + (d << 8) + t] = f2bf(hn);
            u32 hb = f2h(hn);
            u32 ob = (u32)__shfl_xor((int)hb, 1);
            if (!(t & 1)) hp[t >> 1] = hb | (ob << 16);
            hcur = hn;
        }
        __syncthreads();
    }
    if (t < 256) { st[t] = hcur; st[256 + t] = c; }
}

// ---------------------------------------------------------------------------
// Masked mean-pool over time (bf16 in, fp32 atomically accumulated out).
// grid (32, 8), block 256. pooled must be zeroed first.
// ---------------------------------------------------------------------------
__global__ __launch_bounds__(256) void pooled_kernel(
    const bf16_t* __restrict__ L, const int* __restrict__ lens,
    float* __restrict__ pooled)
{
    const int b     = blockIdx.x;
    const int chunk = blockIdx.y;
    const int tid   = threadIdx.x;
    const int len   = lens[b];
    const int t0    = chunk * 250;
    const int t1    = min(t0 + 250, len);
    const float inv = 1.f / fmaxf((float)len, 1.f);
    float s0 = 0.f, s1 = 0.f;
    for (int t = t0; t < t1; ++t) {
        const bf16_t* row = L + (size_t)(b * T_SEQ + t) * 512;
        s0 += bf2f(row[tid]);
        s1 += bf2f(row[tid + 256]);
    }
    if (t1 > t0) {
        atomicAdd(&pooled[b * 512 + tid], s0 * inv);
        atomicAdd(&pooled[b * 512 + 256 + tid], s1 * inv);
    }
}

// ---------------------------------------------------------------------------
// Utterance head: out[b] = relu(pooled@w1.T + b1) @ w2 + b2.  w1T is (512,512)
// transposed so thread u reads w1T[k*512+u] (coalesced). 32 blocks.
// ---------------------------------------------------------------------------
__global__ __launch_bounds__(256) void utt_head(
    const float* __restrict__ pooled,
    const float* __restrict__ w1T, const float* __restrict__ b1,
    const float* __restrict__ w2, const float* __restrict__ b2,
    float* __restrict__ out)
{
    const int b   = blockIdx.x;
    const int tid = threadIdx.x;
    __shared__ float p[512];
    __shared__ float hid[512];
    __shared__ float red[4];
    p[tid]       = pooled[b * 512 + tid];
    p[tid + 256] = pooled[b * 512 + 256 + tid];
    __syncthreads();
#pragma unroll
    for (int half = 0; half < 2; ++half) {
        int u = tid + half * 256;
        float a = b1[u];
#pragma unroll 8
        for (int k = 0; k < 512; ++k) a = fmaf(w1T[(size_t)k * 512 + u], p[k], a);
        hid[u] = fmaxf(a, 0.f);
    }
    __syncthreads();
    float part = hid[tid] * w2[tid] + hid[tid + 256] * w2[tid + 256];
    for (int off = 32; off; off >>= 1) part += __shfl_down(part, off, 64);
    if ((tid & 63) == 0) red[tid >> 6] = part;
    __syncthreads();
    if (tid == 0) out[b] = red[0] + red[1] + red[2] + red[3] + b2[0];
}

// ---------------------------------------------------------------------------
// Fused segment head: mean over [st,en) of bf16 lstm_out -> relu(W1x+b1) -> w2.
// One block per (b,s); w1T transposed for coalesced reads.
// ---------------------------------------------------------------------------
__global__ __launch_bounds__(256) void seg_head(
    const bf16_t* __restrict__ L, const int* __restrict__ lens,
    const int* __restrict__ segs,
    const float* __restrict__ w1T, const float* __restrict__ b1,
    const float* __restrict__ w2, const float* __restrict__ b2,
    const int* __restrict__ seg_lens, float* __restrict__ out)
{
    const int blk = blockIdx.x;
    const int b   = blk / NSEG;
    const int s   = blk - b * NSEG;
    const int tid = threadIdx.x;
    __shared__ float m[512];
    __shared__ float hid[512];
    __shared__ float red[4];
    const int len = lens[b];
    int st = segs[blk * 2 + 0];
    int en = segs[blk * 2 + 1];
    st = min(max(st, 0), len);
    en = max(st + 1, min(en, len));
    const float inv = 1.f / (float)(en - st);
    float a0 = 0.f, a1 = 0.f;
    for (int t = st; t < en; ++t) {
        const bf16_t* row = L + (size_t)(b * T_SEQ + t) * 512;
        a0 += bf2f(row[tid]);
        a1 += bf2f(row[tid + 256]);
    }
    m[tid]       = a0 * inv;
    m[tid + 256] = a1 * inv;
    __syncthreads();
#pragma unroll
    for (int half = 0; half < 2; ++half) {
        int u = tid + half * 256;
        float a = b1[u];
#pragma unroll 8
        for (int k = 0; k < 512; ++k) a = fmaf(w1T[(size_t)k * 512 + u], m[k], a);
        hid[u] = fmaxf(a, 0.f);
    }
    __syncthreads();
    float part = hid[tid] * w2[tid] + hid[tid + 256] * w2[tid + 256];
    for (int off = 32; off; off >>= 1) part += __shfl_down(part, off, 64);
    if ((tid & 63) == 0) red[tid >> 6] = part;
    __syncthreads();
    if (tid == 0)
        out[BATCH + blk] = (s < seg_lens[b]) ? red[0] + red[1] + red[2] + red[3] + b2[0]
                                             : 0.f;
}

// ---------------------------------------------------------------------------
extern "C" void kernel_launch(void* const* d_in, const int* in_sizes, int n_in,
                              void* d_out, int out_size, void* d_ws, size_t ws_size,
                              hipStream_t stream)
{
    const float* features = (const float*)d_in[0];
    const int*   feat_len = (const int*)d_in[1];
    const int*   segs     = (const int*)d_in[2];
    const int*   seg_lens = (const int*)d_in[3];
    const float* conv1_w  = (const float*)d_in[4];
    const float* conv1_b  = (const float*)d_in[5];
    const float* conv2_w  = (const float*)d_in[6];
    const float* conv2_b  = (const float*)d_in[7];
    const float* wih0     = (const float*)d_in[8];
    const float* whh0     = (const float*)d_in[9];
    const float* bias0    = (const float*)d_in[10];
    const float* wih1     = (const float*)d_in[11];
    const float* whh1     = (const float*)d_in[12];
    const float* bias1    = (const float*)d_in[13];
    const float* seg_w1   = (const float*)d_in[14];
    const float* seg_b1   = (const float*)d_in[15];
    const float* seg_w2   = (const float*)d_in[16];
    const float* seg_b2   = (const float*)d_in[17];
    const float* utt_w1   = (const float*)d_in[18];
    const float* utt_b1   = (const float*)d_in[19];
    const float* utt_w2   = (const float*)d_in[20];
    const float* utt_b2   = (const float*)d_in[21];
    float* out = (float*)d_out;
    char*  wsb = (char*)d_ws;

    // ---- byte-granular workspace plan (256B-aligned regions) ----
    size_t off = 0;
    auto alloc = [&](size_t bytes) -> size_t {
        size_t o = off;
        off += (bytes + 255) & ~(size_t)255;
        return o;
    };
    const size_t o_wt1    = alloc(61440  * 4);            // conv1 w (256,240)
    const size_t o_wt2    = alloc(196608 * 4);            // conv2 w (256,768)
    const size_t o_whh0T  = alloc(524288 * 4);            // (2,256,1024)
    const size_t o_whh1T  = alloc(524288 * 4);
    const size_t o_w16_0  = alloc(262144 * 4);            // (2,128,1024) f16x2
    const size_t o_w16_1  = alloc(262144 * 4);
    const size_t o_wp4_0  = alloc((size_t)2 * 2 * NG * 512 * 16);  // b128-packed
    const size_t o_wp4_1  = alloc((size_t)2 * 2 * NG * 512 * 16);
    const size_t o_sw1T   = alloc(262144 * 4);            // seg w1 transposed
    const size_t o_uw1T   = alloc(262144 * 4);            // utt w1 transposed
    const size_t o_state  = alloc(32768  * 4);            // (64,512) h|c
    const size_t o_pooled = alloc(16384  * 4);
    const size_t o_Hcat   = alloc((size_t)32768000 * 2);  // bf16 (B,T,512)
    const size_t o_lstm   = alloc((size_t)32768000 * 2);  // bf16 (B,T,512)
    // y1 (bf16 B,T,256) and x2 (bf16 B,T,256) alias inside the lstm region:
    // both are dead before the layer-1 recurrence writes lstm_out.
    const size_t o_y1     = o_lstm;
    const size_t o_x2     = o_lstm + (size_t)16384000 * 2;
    const size_t fixed_end = off;

    // ---- pick the largest chunk whose Xp buffers fit ----
    const int cands[] = {250, 200, 125, 100, 50, 40, 25, 20, 10};
    int chunk = 0;
    size_t o_XpF = 0, o_XpB = 0;
    for (int ci = 0; ci < 9; ++ci) {
        int c = cands[ci];
        size_t xp_bytes = ((size_t)c * 32 * 1024 * 4 + 255) & ~(size_t)255;
        if (fixed_end + 2 * xp_bytes <= ws_size) {
            chunk = c;
            o_XpF = fixed_end;
            o_XpB = fixed_end + xp_bytes;
            break;
        }
    }
    if (chunk == 0) {
        ws_guard_kernel<<<(out_size + 255) / 256, 256, 0, stream>>>(out, out_size);
        return;
    }
    const int nph = T_SEQ / chunk;

    float*  wt1    = (float*)(wsb + o_wt1);
    float*  wt2    = (float*)(wsb + o_wt2);
    float*  whh0T  = (float*)(wsb + o_whh0T);
    float*  whh1T  = (float*)(wsb + o_whh1T);
    u32*    w16_0  = (u32*)(wsb + o_w16_0);
    u32*    w16_1  = (u32*)(wsb + o_w16_1);
    u32*    wp4_0  = (u32*)(wsb + o_wp4_0);
    u32*    wp4_1  = (u32*)(wsb + o_wp4_1);
    float*  sw1T   = (float*)(wsb + o_sw1T);
    float*  uw1T   = (float*)(wsb + o_uw1T);
    float*  state  = (float*)(wsb + o_state);
    float*  pooled = (float*)(wsb + o_pooled);
    bf16_t* Hcat   = (bf16_t*)(wsb + o_Hcat);
    bf16_t* lstm   = (bf16_t*)(wsb + o_lstm);
    bf16_t* y1     = (bf16_t*)(wsb + o_y1);
    bf16_t* x2     = (bf16_t*)(wsb + o_x2);
    float*  XpF    = (float*)(wsb + o_XpF);
    float*  XpB    = (float*)(wsb + o_XpB);

    hipMemsetAsync(state, 0, 32768 * 4, stream);
    hipMemsetAsync(pooled, 0, 16384 * 4, stream);

    // weight re-layouts
    transpose3<<<240, 256, 0, stream>>>(conv1_w, wt1, 256, 80, 3);
    transpose3<<<768, 256, 0, stream>>>(conv2_w, wt2, 256, 256, 3);
    transpose3<<<2048, 256, 0, stream>>>(whh0, whh0T, 2, 1024, 256);
    transpose3<<<2048, 256, 0, stream>>>(whh1, whh1T, 2, 1024, 256);
    transpose3<<<1024, 256, 0, stream>>>(seg_w1, sw1T, 1, 512, 512);
    transpose3<<<1024, 256, 0, stream>>>(utt_w1, uw1T, 1, 512, 512);
    // pack recurrent weights to f16x2 (reg portion + b128-packed LDS portion)
    pack_whh<<<1024, 256, 0, stream>>>(whh0T, w16_0, wp4_0);
    pack_whh<<<1024, 256, 0, stream>>>(whh1T, w16_1, wp4_1);

    // conv1: (B,T,80) -> bf16 (B,T,256), relu
    gemm_nt<1, 80, float, true><<<dim3(250, 4), 256, 0, stream>>>(
        features, wt1, conv1_b, y1, 64000, 256, 240, 1, 0, 0, feat_len);
    // conv2: bf16 (B,T,256) -> bf16 (B,T,256), relu
    gemm_nt<1, 256, bf16_t, true><<<dim3(250, 4), 256, 0, stream>>>(
        y1, wt2, conv2_b, x2, 64000, 256, 768, 1, 0, 0, feat_len);

    const int gx = (32 * chunk + 255) / 256;

    // ---- layer 0: chunked input projection + recurrence ----
    for (int p = 0; p < nph; ++p) {
        const int t0 = p * chunk;
        gemm_nt<2, 1, bf16_t, false><<<dim3(gx, 16), 256, 0, stream>>>(
            x2, wih0, bias0, XpF, 32 * chunk, 1024, 256, 0, t0, chunk, feat_len);
        gemm_nt<3, 1, bf16_t, false><<<dim3(gx, 16), 256, 0, stream>>>(
            x2, wih0 + 1024 * 256, bias0 + 1024, XpB, 32 * chunk, 1024, 256, 0,
            t0, chunk, feat_len);
        lstm_rec_phase<<<64, 512, 0, stream>>>(
            XpF, XpB, w16_0, (const uint4*)wp4_0, feat_len, state, Hcat, t0, chunk);
    }

    // reset recurrent state for layer 1
    hipMemsetAsync(state, 0, 32768 * 4, stream);

    // ---- layer 1: chunked input projection + recurrence ----
    for (int p = 0; p < nph; ++p) {
        const int t0 = p * chunk;
        gemm_nt<2, 1, bf16_t, false><<<dim3(gx, 16), 256, 0, stream>>>(
            Hcat, wih1, bias1, XpF, 32 * chunk, 1024, 512, 0, t0, chunk, feat_len);
        gemm_nt<3, 1, bf16_t, false><<<dim3(gx, 16), 256, 0, stream>>>(
            Hcat, wih1 + 1024 * 512, bias1 + 1024, XpB, 32 * chunk, 1024, 512, 0,
            t0, chunk, feat_len);
        lstm_rec_phase<<<64, 512, 0, stream>>>(
            XpF, XpB, w16_1, (const uint4*)wp4_1, feat_len, state, lstm, t0, chunk);
    }

    // pooled mean + utterance head
    pooled_kernel<<<dim3(32, 8), 256, 0, stream>>>(lstm, feat_len, pooled);
    utt_head<<<32, 256, 0, stream>>>(pooled, uw1T, utt_b1, utt_w2, utt_b2, out);

    // fused segment means + head
    seg_head<<<3200, 256, 0, stream>>>(lstm, feat_len, segs, sw1T, seg_b1,
                                       seg_w2, seg_b2, seg_lens, out);
}

// Round 6
// 10767.688 us; speedup vs baseline: 3.1974x; 1.0524x over previous
//
#include <hip/hip_runtime.h>
#include <math.h>

#define T_SEQ 2000
#define BATCH 32
#define NSEG  100

typedef unsigned short bf16_t;   // raw bf16 storage
typedef unsigned int   u32;
typedef _Float16       half_t;
typedef half_t half2_t __attribute__((ext_vector_type(2)));

// whh f16 split: KP_REG k-pairs live in VGPRs/AGPRs, KP_LDS k-pairs in LDS.
// KP_REG + KP_LDS == 128 (256 k values).
#define KP_REG 96
#define KP_LDS 32
#define NG     (KP_LDS / 4)        // 8 b128-groups per column

__device__ __forceinline__ float sigmoidf_(float x) {
    return 1.0f / (1.0f + __expf(-x));
}
__device__ __forceinline__ float tanh_(float x) {
    return 1.0f - 2.0f / (__expf(2.0f * x) + 1.0f);
}
__device__ __forceinline__ float bf2f(bf16_t u) {
    return __uint_as_float((unsigned)u << 16);
}
__device__ __forceinline__ bf16_t f2bf(float f) {   // round-to-nearest-even
    unsigned x = __float_as_uint(f);
    return (bf16_t)((x + 0x7FFFu + ((x >> 16) & 1u)) >> 16);
}
// f32 -> f16 bits (RNE via cast)
__device__ __forceinline__ u32 f2h(float f) {
    return (u32)__builtin_bit_cast(unsigned short, (half_t)f);
}
// packed f16x2 dot with f32 accumulate
__device__ __forceinline__ float dot2f(u32 w, u32 h, float acc) {
    return __builtin_amdgcn_fdot2(__builtin_bit_cast(half2_t, w),
                                  __builtin_bit_cast(half2_t, h), acc, false);
}
// broadcast lane's u32 to all lanes (lands in SGPR; fdot2 takes it as scalar)
__device__ __forceinline__ u32 rl(u32 v, int l) {
    return (u32)__builtin_amdgcn_readlane((int)v, l);
}

// 4 consecutive elements -> float4 (fp32 or bf16 source)
__device__ __forceinline__ float4 ld4(const float* p) { return *(const float4*)p; }
__device__ __forceinline__ float4 ld4(const bf16_t* p) {
    ushort4 u = *(const ushort4*)p;
    return make_float4(bf2f(u.x), bf2f(u.y), bf2f(u.z), bf2f(u.w));
}

// ---------------------------------------------------------------------------
// ws too small -> unmistakable signature instead of a fault
// ---------------------------------------------------------------------------
__global__ void ws_guard_kernel(float* out, int n) {
    int i = blockIdx.x * blockDim.x + threadIdx.x;
    if (i < n) out[i] = 1e30f;
}

// ---------------------------------------------------------------------------
// Generic 3D transpose (fp32): in (D0,D1,D2) -> out (D0,D2,D1)
// ---------------------------------------------------------------------------
__global__ void transpose3(const float* __restrict__ in, float* __restrict__ out,
                           int D0, int D1, int D2) {
    int i = blockIdx.x * blockDim.x + threadIdx.x;
    int tot = D0 * D1 * D2;
    if (i >= tot) return;
    int d0 = i / (D1 * D2);
    int r  = i - d0 * (D1 * D2);
    int d1 = r / D2;
    int d2 = r - d1 * D2;
    out[(size_t)d0 * D1 * D2 + (size_t)d2 * D1 + d1] = in[i];
}

// ---------------------------------------------------------------------------
// Pack whhT (2, 256, 1024) f32 ->
//  w16: (2, 128, 1024) u32, u32 = f16x2 over adjacent k  (VGPR-portion loads)
//  wp4: (2, 2, NG, 512) uint4 for the LDS portion (kp >= KP_REG):
//       wp4[d][j&1][g][j>>1].c = f16x2 w[2(KP_REG+4g+c)..+1][j]
//       -> per-thread b128 reads at 16B lane stride (bank-optimal).
// ---------------------------------------------------------------------------
__global__ __launch_bounds__(256) void pack_whh(const float* __restrict__ whhT,
                                                u32* __restrict__ w16,
                                                u32* __restrict__ wp4) {
    int i = blockIdx.x * 256 + threadIdx.x;   // 0 .. 262143
    int d  = i >> 17;
    int r  = i & 131071;
    int kp = r >> 10;
    int j  = r & 1023;
    const float* base = whhT + (size_t)d * 262144;
    u32 lo = f2h(base[(size_t)(2 * kp)     * 1024 + j]);
    u32 hi = f2h(base[(size_t)(2 * kp + 1) * 1024 + j]);
    u32 val = lo | (hi << 16);
    w16[i] = val;
    if (kp >= KP_REG) {
        int g  = (kp - KP_REG) >> 2;
        int cc = (kp - KP_REG) & 3;
        size_t idx = ((((size_t)d * 2 + (j & 1)) * NG + g) * 512 + (j >> 1)) * 4 + cc;
        wp4[idx] = val;
    }
}

// ---------------------------------------------------------------------------
// Tiled GEMM, f16x2-dot2 compute (f32 accumulate):
//   C[m,n] = sum_k A(row(m))[k]*W[n,k] + bias[n]
// MODE 1: conv im2col  A is (B,T,CIN), k = tap*CIN+c, pad=1
// MODE 2: chunk-fwd    m=(bb,r), A row = bb*T_SEQ + (t0+r)
// MODE 3: chunk-bwd    m=(bb,r), A row = bb*T_SEQ + (lens[bb]-1-(t0+r))
// MODE 4: dual-dir     blockIdx.z=0 -> MODE2 into Cout; z=1 -> MODE3 into
//                      Cout2 with W += N*K, bias += N (dir-1 weight block).
// TA: float | bf16_t (A storage).  OUT_BF: store C as bf16.
// Tile: 256(M) x 64(N) x 32(K); 256 thr; 8x8 micro-tile.
// A/W staged in LDS as f16x2 k-pairs: inner loop = 16 kp-iters x 64 dot2
// (2 MAC/instr -> 2x the fp32-fma path; f16's 2^-11 mantissa is finer than
// the bf16 2^-8 the activations are stored in, so no accuracy regression).
// LDS 21 KB -> ~7 blocks/CU.
// ---------------------------------------------------------------------------
template <int MODE, int CIN, typename TA, bool OUT_BF>
__global__ __launch_bounds__(256) void gemm_nt(
    const TA* __restrict__ A, const float* __restrict__ W,
    const float* __restrict__ bias, void* __restrict__ Cout,
    void* __restrict__ Cout2,
    int M, int N, int K, int relu, int t0, int chunkM,
    const int* __restrict__ lens)
{
    __shared__ u32 As[16 * 258];
    __shared__ u32 Ws[16 * 66];
    const int tid    = threadIdx.x;
    const int m_base = blockIdx.x * 256;
    const int n_base = blockIdx.y * 64;
    const int m0     = (tid >> 3) * 8;   // 0..248
    const int n0     = (tid & 7) * 8;    // 0..56
    int zrev = 0;
    if constexpr (MODE == 4) {
        zrev = blockIdx.z;
        if (zrev) { W += (size_t)N * K; bias += N; Cout = Cout2; }
    }
    float acc[8][8] = {};

    for (int k0 = 0; k0 < K; k0 += 32) {
        // ---- stage A tile (256 rows x 32 k = 16 k-pairs), f16x2 packed ----
#pragma unroll
        for (int i = 0; i < 8; ++i) {
            int f4  = i * 256 + tid;
            int row = f4 >> 3;          // 0..255
            int k4  = (f4 & 7) << 2;    // 0..28
            int gm  = m_base + row;
            int gk  = k0 + k4;
            float4 v = make_float4(0.f, 0.f, 0.f, 0.f);
            if (gm < M && gk < K) {
                if constexpr (MODE == 1) {
                    int bb  = gm / T_SEQ;
                    int tt  = gm - bb * T_SEQ;
                    int tap = gk / CIN;
                    int cc  = gk - tap * CIN;
                    int ts  = tt + tap - 1;
                    if (ts >= 0 && ts < T_SEQ)
                        v = ld4(A + ((size_t)(bb * T_SEQ + ts) * CIN + cc));
                } else {
                    int bb = gm / chunkM;
                    int r  = gm - bb * chunkM;
                    int t;
                    if constexpr (MODE == 2)      t = t0 + r;
                    else if constexpr (MODE == 3) t = lens[bb] - 1 - (t0 + r);
                    else t = zrev ? (lens[bb] - 1 - (t0 + r)) : (t0 + r);
                    if (t >= 0 && t < T_SEQ)
                        v = ld4(A + ((size_t)(bb * T_SEQ + t) * K + gk));
                }
            }
            int kp = k4 >> 1;           // 0,2,4,..,14
            As[(kp + 0) * 258 + row] = f2h(v.x) | (f2h(v.y) << 16);
            As[(kp + 1) * 258 + row] = f2h(v.z) | (f2h(v.w) << 16);
        }
        // ---- stage W tile (64 rows x 32 k), f16x2 packed ----
#pragma unroll
        for (int i = 0; i < 2; ++i) {
            int f4  = i * 256 + tid;
            int row = f4 >> 3;          // 0..63
            int k4  = (f4 & 7) << 2;
            int gn  = n_base + row;
            int gk  = k0 + k4;
            float4 v = make_float4(0.f, 0.f, 0.f, 0.f);
            if (gk < K)
                v = *(const float4*)(W + (size_t)gn * K + gk);
            int kp = k4 >> 1;
            Ws[(kp + 0) * 66 + row] = f2h(v.x) | (f2h(v.y) << 16);
            Ws[(kp + 1) * 66 + row] = f2h(v.z) | (f2h(v.w) << 16);
        }
        __syncthreads();
        // ---- inner product: 16 k-pairs x 8x8 dot2 ----
#pragma unroll 8
        for (int kk = 0; kk < 16; ++kk) {
            u32 am[8], wn[8];
#pragma unroll
            for (int j = 0; j < 4; ++j) {
                uint2 a = *(const uint2*)(As + kk * 258 + m0 + 2 * j);
                am[2 * j] = a.x; am[2 * j + 1] = a.y;
                uint2 w = *(const uint2*)(Ws + kk * 66 + n0 + 2 * j);
                wn[2 * j] = w.x; wn[2 * j + 1] = w.y;
            }
#pragma unroll
            for (int im = 0; im < 8; ++im)
#pragma unroll
                for (int in = 0; in < 8; ++in)
                    acc[im][in] = dot2f(am[im], wn[in], acc[im][in]);
        }
        __syncthreads();
    }

    // ---- epilogue: bias (+relu) ----
    float bs[8];
#pragma unroll
    for (int j = 0; j < 8; ++j) bs[j] = bias[n_base + n0 + j];
#pragma unroll
    for (int im = 0; im < 8; ++im) {
        int gm = m_base + m0 + im;
        if (gm < M) {
            float o[8];
#pragma unroll
            for (int j = 0; j < 8; ++j) {
                float v = acc[im][j] + bs[j];
                o[j] = relu ? fmaxf(v, 0.f) : v;
            }
            if constexpr (OUT_BF) {
                bf16_t* crow = (bf16_t*)Cout + (size_t)gm * N + n_base + n0;
                ushort4 u0 = { f2bf(o[0]), f2bf(o[1]), f2bf(o[2]), f2bf(o[3]) };
                ushort4 u1 = { f2bf(o[4]), f2bf(o[5]), f2bf(o[6]), f2bf(o[7]) };
                *(ushort4*)(crow)     = u0;
                *(ushort4*)(crow + 4) = u1;
            } else {
                float* crow = (float*)Cout + (size_t)gm * N + n_base + n0;
                *(float4*)(crow)     = make_float4(o[0], o[1], o[2], o[3]);
                *(float4*)(crow + 4) = make_float4(o[4], o[5], o[6], o[7]);
            }
        }
    }
}

// ---------------------------------------------------------------------------
// LSTM recurrence, one phase of `chunk` steps. One block (512 thr) per (b,dir).
// VERIFIED round-4 kernel (11.33 ms run, absmax 3.05e-4) — unchanged.
//
// whh on-chip for the whole phase: kp<KP_REG in registers (192 dwords/thread),
// kp>=KP_REG in LDS (128 KB, b128-packed per column pair). h broadcast via
// v_readlane -> SGPR consumed directly by v_dot2_f32_f16.
// ---------------------------------------------------------------------------
__global__
__attribute__((amdgpu_flat_work_group_size(512, 512), amdgpu_waves_per_eu(2, 2)))
void lstm_rec_phase(
    const float* __restrict__ XpF, const float* __restrict__ XpB,
    const u32* __restrict__ whh16, const uint4* __restrict__ wp4,
    const int* __restrict__ lens,
    float* __restrict__ state, bf16_t* __restrict__ Hout, int s0, int chunk)
{
    __shared__ __align__(16) uint4 wlds4[2 * NG * 512];   // 128 KB
    __shared__ __align__(16) float gs[1024];
    __shared__ __align__(16) u32   hp[128];

    const int bd   = blockIdx.x;
    const int b    = bd >> 1;
    const int d    = bd & 1;
    const int t    = threadIdx.x;      // 0..511
    const int j0   = t * 2;
    const int lane = t & 63;
    const int len  = lens[b];
    const int s1   = min(s0 + chunk, len);
    const u32*   Wg = whh16 + (size_t)d * (128 * 1024);
    const uint4* Wp = wp4   + (size_t)d * (2 * NG * 512);

    // ---- load whh f16x2: registers (kp < KP_REG) + LDS (rest, b128-packed) --
    uint2 w2[KP_REG];                 // .x: col j0, .y: col j0+1
#pragma unroll
    for (int kp = 0; kp < KP_REG; ++kp)
        w2[kp] = *(const uint2*)(Wg + (size_t)kp * 1024 + j0);
#pragma unroll
    for (int i = 0; i < 2 * NG; ++i)
        wlds4[i * 512 + t] = Wp[i * 512 + t];

    // ---- init state + packed h ----
    float* st = state + bd * 512;
    float c = 0.f, hcur = 0.f;
    if (t < 256) {
        if (s0 > 0) { hcur = st[t]; c = st[256 + t]; }
        u32 hb = f2h(hcur);
        u32 ob = (u32)__shfl_xor((int)hb, 1);
        if (!(t & 1)) hp[t >> 1] = hb | (ob << 16);
    }
    __syncthreads();

    const float* xrow = ((d ? XpB : XpF) + (size_t)b * ((size_t)chunk * 1024));
    const uint4* wpA = wlds4 + t;                 // col j0 groups
    const uint4* wpB = wlds4 + NG * 512 + t;      // col j0+1 groups
    for (int s = s0; s < s1; ++s, xrow += 1024) {
        float2 xv = *(const float2*)(xrow + j0);          // early issue
        uint2 hreg = *(const uint2*)(hp + 2 * lane);      // own 8B of h
        float a0 = 0.f, a1 = 0.f, b0 = 0.f, b1 = 0.f;
#pragma unroll
        for (int kp = 0; kp < KP_REG; kp += 2) {          // 48 iters
            u32 h0 = rl(hreg.x, kp >> 1);                 // hp[kp]
            u32 h1 = rl(hreg.y, kp >> 1);                 // hp[kp+1]
            a0 = dot2f(w2[kp].x,     h0, a0); a1 = dot2f(w2[kp].y,     h0, a1);
            b0 = dot2f(w2[kp + 1].x, h1, b0); b1 = dot2f(w2[kp + 1].y, h1, b1);
        }
#pragma unroll
        for (int g = 0; g < NG; ++g) {                    // 8 iters
            uint4 wA = wpA[g * 512];
            uint4 wB = wpB[g * 512];
            const int lb = (KP_REG >> 1) + 2 * g;         // base lane for hp
            u32 h0 = rl(hreg.x, lb);                      // hp[KP_REG+4g]
            u32 h1 = rl(hreg.y, lb);                      // +1
            u32 h2 = rl(hreg.x, lb + 1);                  // +2
            u32 h3 = rl(hreg.y, lb + 1);                  // +3
            a0 = dot2f(wA.x, h0, a0); a1 = dot2f(wB.x, h0, a1);
            b0 = dot2f(wA.y, h1, b0); b1 = dot2f(wB.y, h1, b1);
            a0 = dot2f(wA.z, h2, a0); a1 = dot2f(wB.z, h2, a1);
            b0 = dot2f(wA.w, h3, b0); b1 = dot2f(wB.w, h3, b1);
        }
        *(float2*)(gs + j0) = make_float2(a0 + b0 + xv.x, a1 + b1 + xv.y);
        __syncthreads();
        if (t < 256) {
            float ig = sigmoidf_(gs[t]);
            float fg = sigmoidf_(gs[256 + t]);
            float gg = tanh_(gs[512 + t]);
            float og = sigmoidf_(gs[768 + t]);
            c = fmaf(fg, c, ig * gg);
            float hn = og * tanh_(c);
            const int tau = d ? (len - 1 - s) : s;
            Hout[(size_t)(b * T_SEQ + tau) * 512 + (d << 8) + t] = f2bf(hn);
            u32 hb = f2h(hn);
            u32 ob = (u32)__shfl_xor((int)hb, 1);
            if (!(t & 1)) hp[t >> 1] = hb | (ob << 16);
            hcur = hn;
        }
        __syncthreads();
    }
    if (t < 256) { st[t] = hcur; st[256 + t] = c; }
}

// ---------------------------------------------------------------------------
// Masked mean-pool over time (bf16 in, fp32 atomically accumulated out).
// grid (32, 8), block 256. pooled must be zeroed first.
// ---------------------------------------------------------------------------
__global__ __launch_bounds__(256) void pooled_kernel(
    const bf16_t* __restrict__ L, const int* __restrict__ lens,
    float* __restrict__ pooled)
{
    const int b     = blockIdx.x;
    const int chunk = blockIdx.y;
    const int tid   = threadIdx.x;
    const int len   = lens[b];
    const int t0    = chunk * 250;
    const int t1    = min(t0 + 250, len);
    const float inv = 1.f / fmaxf((float)len, 1.f);
    float s0 = 0.f, s1 = 0.f;
    for (int t = t0; t < t1; ++t) {
        const bf16_t* row = L + (size_t)(b * T_SEQ + t) * 512;
        s0 += bf2f(row[tid]);
        s1 += bf2f(row[tid + 256]);
    }
    if (t1 > t0) {
        atomicAdd(&pooled[b * 512 + tid], s0 * inv);
        atomicAdd(&pooled[b * 512 + 256 + tid], s1 * inv);
    }
}

// ---------------------------------------------------------------------------
// Utterance head: out[b] = relu(pooled@w1.T + b1) @ w2 + b2.  w1T is (512,512)
// transposed so thread u reads w1T[k*512+u] (coalesced). 32 blocks.
// ---------------------------------------------------------------------------
__global__ __launch_bounds__(256) void utt_head(
    const float* __restrict__ pooled,
    const float* __restrict__ w1T, const float* __restrict__ b1,
    const float* __restrict__ w2, const float* __restrict__ b2,
    float* __restrict__ out)
{
    const int b   = blockIdx.x;
    const int tid = threadIdx.x;
    __shared__ float p[512];
    __shared__ float hid[512];
    __shared__ float red[4];
    p[tid]       = pooled[b * 512 + tid];
    p[tid + 256] = pooled[b * 512 + 256 + tid];
    __syncthreads();
#pragma unroll
    for (int half = 0; half < 2; ++half) {
        int u = tid + half * 256;
        float a = b1[u];
#pragma unroll 8
        for (int k = 0; k < 512; ++k) a = fmaf(w1T[(size_t)k * 512 + u], p[k], a);
        hid[u] = fmaxf(a, 0.f);
    }
    __syncthreads();
    float part = hid[tid] * w2[tid] + hid[tid + 256] * w2[tid + 256];
    for (int off = 32; off; off >>= 1) part += __shfl_down(part, off, 64);
    if ((tid & 63) == 0) red[tid >> 6] = part;
    __syncthreads();
    if (tid == 0) out[b] = red[0] + red[1] + red[2] + red[3] + b2[0];
}

// ---------------------------------------------------------------------------
// Fused segment head: mean over [st,en) of bf16 lstm_out -> relu(W1x+b1) -> w2.
// One block per (b,s); w1T transposed for coalesced reads.
// ---------------------------------------------------------------------------
__global__ __launch_bounds__(256) void seg_head(
    const bf16_t* __restrict__ L, const int* __restrict__ lens,
    const int* __restrict__ segs,
    const float* __restrict__ w1T, const float* __restrict__ b1,
    const float* __restrict__ w2, const float* __restrict__ b2,
    const int* __restrict__ seg_lens, float* __restrict__ out)
{
    const int blk = blockIdx.x;
    const int b   = blk / NSEG;
    const int s   = blk - b * NSEG;
    const int tid = threadIdx.x;
    __shared__ float m[512];
    __shared__ float hid[512];
    __shared__ float red[4];
    const int len = lens[b];
    int st = segs[blk * 2 + 0];
    int en = segs[blk * 2 + 1];
    st = min(max(st, 0), len);
    en = max(st + 1, min(en, len));
    const float inv = 1.f / (float)(en - st);
    float a0 = 0.f, a1 = 0.f;
    for (int t = st; t < en; ++t) {
        const bf16_t* row = L + (size_t)(b * T_SEQ + t) * 512;
        a0 += bf2f(row[tid]);
        a1 += bf2f(row[tid + 256]);
    }
    m[tid]       = a0 * inv;
    m[tid + 256] = a1 * inv;
    __syncthreads();
#pragma unroll
    for (int half = 0; half < 2; ++half) {
        int u = tid + half * 256;
        float a = b1[u];
#pragma unroll 8
        for (int k = 0; k < 512; ++k) a = fmaf(w1T[(size_t)k * 512 + u], m[k], a);
        hid[u] = fmaxf(a, 0.f);
    }
    __syncthreads();
    float part = hid[tid] * w2[tid] + hid[tid + 256] * w2[tid + 256];
    for (int off = 32; off; off >>= 1) part += __shfl_down(part, off, 64);
    if ((tid & 63) == 0) red[tid >> 6] = part;
    __syncthreads();
    if (tid == 0)
        out[BATCH + blk] = (s < seg_lens[b]) ? red[0] + red[1] + red[2] + red[3] + b2[0]
                                             : 0.f;
}

// ---------------------------------------------------------------------------
extern "C" void kernel_launch(void* const* d_in, const int* in_sizes, int n_in,
                              void* d_out, int out_size, void* d_ws, size_t ws_size,
                              hipStream_t stream)
{
    const float* features = (const float*)d_in[0];
    const int*   feat_len = (const int*)d_in[1];
    const int*   segs     = (const int*)d_in[2];
    const int*   seg_lens = (const int*)d_in[3];
    const float* conv1_w  = (const float*)d_in[4];
    const float* conv1_b  = (const float*)d_in[5];
    const float* conv2_w  = (const float*)d_in[6];
    const float* conv2_b  = (const float*)d_in[7];
    const float* wih0     = (const float*)d_in[8];
    const float* whh0     = (const float*)d_in[9];
    const float* bias0    = (const float*)d_in[10];
    const float* wih1     = (const float*)d_in[11];
    const float* whh1     = (const float*)d_in[12];
    const float* bias1    = (const float*)d_in[13];
    const float* seg_w1   = (const float*)d_in[14];
    const float* seg_b1   = (const float*)d_in[15];
    const float* seg_w2   = (const float*)d_in[16];
    const float* seg_b2   = (const float*)d_in[17];
    const float* utt_w1   = (const float*)d_in[18];
    const float* utt_b1   = (const float*)d_in[19];
    const float* utt_w2   = (const float*)d_in[20];
    const float* utt_b2   = (const float*)d_in[21];
    float* out = (float*)d_out;
    char*  wsb = (char*)d_ws;

    // ---- byte-granular workspace plan (256B-aligned regions) ----
    size_t off = 0;
    auto alloc = [&](size_t bytes) -> size_t {
        size_t o = off;
        off += (bytes + 255) & ~(size_t)255;
        return o;
    };
    const size_t o_wt1    = alloc(61440  * 4);            // conv1 w (256,240)
    const size_t o_wt2    = alloc(196608 * 4);            // conv2 w (256,768)
    const size_t o_whh0T  = alloc(524288 * 4);            // (2,256,1024)
    const size_t o_whh1T  = alloc(524288 * 4);
    const size_t o_w16_0  = alloc(262144 * 4);            // (2,128,1024) f16x2
    const size_t o_w16_1  = alloc(262144 * 4);
    const size_t o_wp4_0  = alloc((size_t)2 * 2 * NG * 512 * 16);  // b128-packed
    const size_t o_wp4_1  = alloc((size_t)2 * 2 * NG * 512 * 16);
    const size_t o_sw1T   = alloc(262144 * 4);            // seg w1 transposed
    const size_t o_uw1T   = alloc(262144 * 4);            // utt w1 transposed
    const size_t o_state  = alloc(32768  * 4);            // (64,512) h|c
    const size_t o_pooled = alloc(16384  * 4);
    const size_t o_Hcat   = alloc((size_t)32768000 * 2);  // bf16 (B,T,512)
    const size_t o_lstm   = alloc((size_t)32768000 * 2);  // bf16 (B,T,512)
    // y1 (bf16 B,T,256) and x2 (bf16 B,T,256) alias inside the lstm region:
    // both are dead before the layer-1 recurrence writes lstm_out.
    const size_t o_y1     = o_lstm;
    const size_t o_x2     = o_lstm + (size_t)16384000 * 2;
    const size_t fixed_end = off;

    // ---- pick the largest chunk whose 2 Xp buffers fit ----
    const int cands[] = {250, 200, 125, 100, 50, 40, 25, 20, 10};
    int chunk = 0;
    size_t o_XpF = 0, o_XpB = 0;
    for (int ci = 0; ci < 9; ++ci) {
        int c = cands[ci];
        size_t xp_bytes = ((size_t)c * 32 * 1024 * 4 + 255) & ~(size_t)255;
        if (fixed_end + 2 * xp_bytes <= ws_size) {
            chunk = c;
            o_XpF = fixed_end;
            o_XpB = fixed_end + xp_bytes;
            break;
        }
    }
    if (chunk == 0) {
        ws_guard_kernel<<<(out_size + 255) / 256, 256, 0, stream>>>(out, out_size);
        return;
    }
    const int nph = T_SEQ / chunk;

    float*  wt1    = (float*)(wsb + o_wt1);
    float*  wt2    = (float*)(wsb + o_wt2);
    float*  whh0T  = (float*)(wsb + o_whh0T);
    float*  whh1T  = (float*)(wsb + o_whh1T);
    u32*    w16_0  = (u32*)(wsb + o_w16_0);
    u32*    w16_1  = (u32*)(wsb + o_w16_1);
    u32*    wp4_0  = (u32*)(wsb + o_wp4_0);
    u32*    wp4_1  = (u32*)(wsb + o_wp4_1);
    float*  sw1T   = (float*)(wsb + o_sw1T);
    float*  uw1T   = (float*)(wsb + o_uw1T);
    float*  state  = (float*)(wsb + o_state);
    float*  pooled = (float*)(wsb + o_pooled);
    bf16_t* Hcat   = (bf16_t*)(wsb + o_Hcat);
    bf16_t* lstm   = (bf16_t*)(wsb + o_lstm);
    bf16_t* y1     = (bf16_t*)(wsb + o_y1);
    bf16_t* x2     = (bf16_t*)(wsb + o_x2);
    float*  XpF    = (float*)(wsb + o_XpF);
    float*  XpB    = (float*)(wsb + o_XpB);

    hipMemsetAsync(state, 0, 32768 * 4, stream);
    hipMemsetAsync(pooled, 0, 16384 * 4, stream);

    // weight re-layouts
    transpose3<<<240, 256, 0, stream>>>(conv1_w, wt1, 256, 80, 3);
    transpose3<<<768, 256, 0, stream>>>(conv2_w, wt2, 256, 256, 3);
    transpose3<<<2048, 256, 0, stream>>>(whh0, whh0T, 2, 1024, 256);
    transpose3<<<2048, 256, 0, stream>>>(whh1, whh1T, 2, 1024, 256);
    transpose3<<<1024, 256, 0, stream>>>(seg_w1, sw1T, 1, 512, 512);
    transpose3<<<1024, 256, 0, stream>>>(utt_w1, uw1T, 1, 512, 512);
    // pack recurrent weights to f16x2 (reg portion + b128-packed LDS portion)
    pack_whh<<<1024, 256, 0, stream>>>(whh0T, w16_0, wp4_0);
    pack_whh<<<1024, 256, 0, stream>>>(whh1T, w16_1, wp4_1);

    // conv1: (B,T,80) -> bf16 (B,T,256), relu
    gemm_nt<1, 80, float, true><<<dim3(250, 4), 256, 0, stream>>>(
        features, wt1, conv1_b, y1, nullptr, 64000, 256, 240, 1, 0, 0, feat_len);
    // conv2: bf16 (B,T,256) -> bf16 (B,T,256), relu
    gemm_nt<1, 256, bf16_t, true><<<dim3(250, 4), 256, 0, stream>>>(
        y1, wt2, conv2_b, x2, nullptr, 64000, 256, 768, 1, 0, 0, feat_len);

    const int gx = (32 * chunk + 255) / 256;
    const int Mc = 32 * chunk;

    // ---- layer 0: chunked dual-dir input projection + recurrence ----
    for (int p = 0; p < nph; ++p) {
        const int t0 = p * chunk;
        gemm_nt<4, 1, bf16_t, false><<<dim3(gx, 16, 2), 256, 0, stream>>>(
            x2, wih0, bias0, XpF, XpB, Mc, 1024, 256, 0, t0, chunk, feat_len);
        lstm_rec_phase<<<64, 512, 0, stream>>>(
            XpF, XpB, w16_0, (const uint4*)wp4_0, feat_len, state, Hcat, t0, chunk);
    }

    // reset recurrent state for layer 1
    hipMemsetAsync(state, 0, 32768 * 4, stream);

    // ---- layer 1: chunked dual-dir input projection + recurrence ----
    for (int p = 0; p < nph; ++p) {
        const int t0 = p * chunk;
        gemm_nt<4, 1, bf16_t, false><<<dim3(gx, 16, 2), 256, 0, stream>>>(
            Hcat, wih1, bias1, XpF, XpB, Mc, 1024, 512, 0, t0, chunk, feat_len);
        lstm_rec_phase<<<64, 512, 0, stream>>>(
            XpF, XpB, w16_1, (const uint4*)wp4_1, feat_len, state, lstm, t0, chunk);
    }

    // pooled mean + utterance head
    pooled_kernel<<<dim3(32, 8), 256, 0, stream>>>(lstm, feat_len, pooled);
    utt_head<<<32, 256, 0, stream>>>(pooled, uw1T, utt_b1, utt_w2, utt_b2, out);

    // fused segment means + head
    seg_head<<<3200, 256, 0, stream>>>(lstm, feat_len, segs, sw1T, seg_b1,
                                       seg_w2, seg_b2, seg_lens, out);
}

// Round 7
// 8624.747 us; speedup vs baseline: 3.9918x; 1.2485x over previous
//
#include <hip/hip_runtime.h>
#include <math.h>

#define T_SEQ 2000
#define BATCH 32
#define NSEG  100

typedef unsigned short bf16_t;   // raw bf16 storage
typedef unsigned int   u32;
typedef _Float16       half_t;
typedef half_t half2_t __attribute__((ext_vector_type(2)));

// whh f16 split: KP_REG k-pairs live in VGPRs/AGPRs, KP_LDS k-pairs in LDS.
// KP_REG + KP_LDS == 128 (256 k values).
#define KP_REG 96
#define KP_LDS 32
#define NG     (KP_LDS / 4)        // 8 b128-groups per column

__device__ __forceinline__ float sigmoidf_(float x) {
    return 1.0f / (1.0f + __expf(-x));
}
__device__ __forceinline__ float tanh_(float x) {
    return 1.0f - 2.0f / (__expf(2.0f * x) + 1.0f);
}
__device__ __forceinline__ float bf2f(bf16_t u) {
    return __uint_as_float((unsigned)u << 16);
}
__device__ __forceinline__ bf16_t f2bf(float f) {   // round-to-nearest-even
    unsigned x = __float_as_uint(f);
    return (bf16_t)((x + 0x7FFFu + ((x >> 16) & 1u)) >> 16);
}
// f32 -> f16 bits (RNE via cast)
__device__ __forceinline__ u32 f2h(float f) {
    return (u32)__builtin_bit_cast(unsigned short, (half_t)f);
}
// packed f16x2 dot with f32 accumulate
__device__ __forceinline__ float dot2f(u32 w, u32 h, float acc) {
    return __builtin_amdgcn_fdot2(__builtin_bit_cast(half2_t, w),
                                  __builtin_bit_cast(half2_t, h), acc, false);
}
// broadcast lane's u32 to all lanes (lands in SGPR; fdot2 takes it as scalar)
__device__ __forceinline__ u32 rl(u32 v, int l) {
    return (u32)__builtin_amdgcn_readlane((int)v, l);
}

// 4 consecutive elements -> float4 (fp32 or bf16 source)
__device__ __forceinline__ float4 ld4(const float* p) { return *(const float4*)p; }
__device__ __forceinline__ float4 ld4(const bf16_t* p) {
    ushort4 u = *(const ushort4*)p;
    return make_float4(bf2f(u.x), bf2f(u.y), bf2f(u.z), bf2f(u.w));
}

// ---------------------------------------------------------------------------
// ws too small -> unmistakable signature instead of a fault
// ---------------------------------------------------------------------------
__global__ void ws_guard_kernel(float* out, int n) {
    int i = blockIdx.x * blockDim.x + threadIdx.x;
    if (i < n) out[i] = 1e30f;
}

// ---------------------------------------------------------------------------
// Generic 3D transpose (fp32): in (D0,D1,D2) -> out (D0,D2,D1)
// ---------------------------------------------------------------------------
__global__ void transpose3(const float* __restrict__ in, float* __restrict__ out,
                           int D0, int D1, int D2) {
    int i = blockIdx.x * blockDim.x + threadIdx.x;
    int tot = D0 * D1 * D2;
    if (i >= tot) return;
    int d0 = i / (D1 * D2);
    int r  = i - d0 * (D1 * D2);
    int d1 = r / D2;
    int d2 = r - d1 * D2;
    out[(size_t)d0 * D1 * D2 + (size_t)d2 * D1 + d1] = in[i];
}

// ---------------------------------------------------------------------------
// Pack whhT (2, 256, 1024) f32 ->
//  w16: (2, 128, 1024) u32, u32 = f16x2 over adjacent k  (VGPR-portion loads)
//  wp4: (2, 2, NG, 512) uint4 for the LDS portion (kp >= KP_REG):
//       per-thread b128 reads at 16B lane stride (bank-optimal).
// ---------------------------------------------------------------------------
__global__ __launch_bounds__(256) void pack_whh(const float* __restrict__ whhT,
                                                u32* __restrict__ w16,
                                                u32* __restrict__ wp4) {
    int i = blockIdx.x * 256 + threadIdx.x;   // 0 .. 262143
    int d  = i >> 17;
    int r  = i & 131071;
    int kp = r >> 10;
    int j  = r & 1023;
    const float* base = whhT + (size_t)d * 262144;
    u32 lo = f2h(base[(size_t)(2 * kp)     * 1024 + j]);
    u32 hi = f2h(base[(size_t)(2 * kp + 1) * 1024 + j]);
    u32 val = lo | (hi << 16);
    w16[i] = val;
    if (kp >= KP_REG) {
        int g  = (kp - KP_REG) >> 2;
        int cc = (kp - KP_REG) & 3;
        size_t idx = ((((size_t)d * 2 + (j & 1)) * NG + g) * 512 + (j >> 1)) * 4 + cc;
        wp4[idx] = val;
    }
}

// ---------------------------------------------------------------------------
// Tiled GEMM, f16x2-dot2 compute (f32 accumulate). VERIFIED round-6 kernel.
// MODE 1: conv im2col  A is (B,T,CIN), k = tap*CIN+c, pad=1
// MODE 4: dual-dir     blockIdx.z=0 -> fwd into Cout; z=1 -> time-reversed
//                      into Cout2 with W += N*K, bias += N.
// Tile: 256(M) x 64(N) x 32(K); 256 thr; 8x8 micro-tile.
// ---------------------------------------------------------------------------
template <int MODE, int CIN, typename TA, bool OUT_BF>
__global__ __launch_bounds__(256) void gemm_nt(
    const TA* __restrict__ A, const float* __restrict__ W,
    const float* __restrict__ bias, void* __restrict__ Cout,
    void* __restrict__ Cout2,
    int M, int N, int K, int relu, int t0, int chunkM,
    const int* __restrict__ lens)
{
    __shared__ u32 As[16 * 258];
    __shared__ u32 Ws[16 * 66];
    const int tid    = threadIdx.x;
    const int m_base = blockIdx.x * 256;
    const int n_base = blockIdx.y * 64;
    const int m0     = (tid >> 3) * 8;   // 0..248
    const int n0     = (tid & 7) * 8;    // 0..56
    int zrev = 0;
    if constexpr (MODE == 4) {
        zrev = blockIdx.z;
        if (zrev) { W += (size_t)N * K; bias += N; Cout = Cout2; }
    }
    float acc[8][8] = {};

    for (int k0 = 0; k0 < K; k0 += 32) {
#pragma unroll
        for (int i = 0; i < 8; ++i) {
            int f4  = i * 256 + tid;
            int row = f4 >> 3;          // 0..255
            int k4  = (f4 & 7) << 2;    // 0..28
            int gm  = m_base + row;
            int gk  = k0 + k4;
            float4 v = make_float4(0.f, 0.f, 0.f, 0.f);
            if (gm < M && gk < K) {
                if constexpr (MODE == 1) {
                    int bb  = gm / T_SEQ;
                    int tt  = gm - bb * T_SEQ;
                    int tap = gk / CIN;
                    int cc  = gk - tap * CIN;
                    int ts  = tt + tap - 1;
                    if (ts >= 0 && ts < T_SEQ)
                        v = ld4(A + ((size_t)(bb * T_SEQ + ts) * CIN + cc));
                } else {
                    int bb = gm / chunkM;
                    int r  = gm - bb * chunkM;
                    int t  = zrev ? (lens[bb] - 1 - (t0 + r)) : (t0 + r);
                    if (t >= 0 && t < T_SEQ)
                        v = ld4(A + ((size_t)(bb * T_SEQ + t) * K + gk));
                }
            }
            int kp = k4 >> 1;           // 0,2,4,..,14
            As[(kp + 0) * 258 + row] = f2h(v.x) | (f2h(v.y) << 16);
            As[(kp + 1) * 258 + row] = f2h(v.z) | (f2h(v.w) << 16);
        }
#pragma unroll
        for (int i = 0; i < 2; ++i) {
            int f4  = i * 256 + tid;
            int row = f4 >> 3;          // 0..63
            int k4  = (f4 & 7) << 2;
            int gn  = n_base + row;
            int gk  = k0 + k4;
            float4 v = make_float4(0.f, 0.f, 0.f, 0.f);
            if (gk < K)
                v = *(const float4*)(W + (size_t)gn * K + gk);
            int kp = k4 >> 1;
            Ws[(kp + 0) * 66 + row] = f2h(v.x) | (f2h(v.y) << 16);
            Ws[(kp + 1) * 66 + row] = f2h(v.z) | (f2h(v.w) << 16);
        }
        __syncthreads();
#pragma unroll 8
        for (int kk = 0; kk < 16; ++kk) {
            u32 am[8], wn[8];
#pragma unroll
            for (int j = 0; j < 4; ++j) {
                uint2 a = *(const uint2*)(As + kk * 258 + m0 + 2 * j);
                am[2 * j] = a.x; am[2 * j + 1] = a.y;
                uint2 w = *(const uint2*)(Ws + kk * 66 + n0 + 2 * j);
                wn[2 * j] = w.x; wn[2 * j + 1] = w.y;
            }
#pragma unroll
            for (int im = 0; im < 8; ++im)
#pragma unroll
                for (int in = 0; in < 8; ++in)
                    acc[im][in] = dot2f(am[im], wn[in], acc[im][in]);
        }
        __syncthreads();
    }

    float bs[8];
#pragma unroll
    for (int j = 0; j < 8; ++j) bs[j] = bias[n_base + n0 + j];
#pragma unroll
    for (int im = 0; im < 8; ++im) {
        int gm = m_base + m0 + im;
        if (gm < M) {
            float o[8];
#pragma unroll
            for (int j = 0; j < 8; ++j) {
                float v = acc[im][j] + bs[j];
                o[j] = relu ? fmaxf(v, 0.f) : v;
            }
            if constexpr (OUT_BF) {
                bf16_t* crow = (bf16_t*)Cout + (size_t)gm * N + n_base + n0;
                ushort4 u0 = { f2bf(o[0]), f2bf(o[1]), f2bf(o[2]), f2bf(o[3]) };
                ushort4 u1 = { f2bf(o[4]), f2bf(o[5]), f2bf(o[6]), f2bf(o[7]) };
                *(ushort4*)(crow)     = u0;
                *(ushort4*)(crow + 4) = u1;
            } else {
                float* crow = (float*)Cout + (size_t)gm * N + n_base + n0;
                *(float4*)(crow)     = make_float4(o[0], o[1], o[2], o[3]);
                *(float4*)(crow + 4) = make_float4(o[4], o[5], o[6], o[7]);
            }
        }
    }
}

// ---------------------------------------------------------------------------
// FUSED dispatch: LSTM recurrence phase p  +  projection GEMM for phase p+1.
// 256 blocks x 512 threads; LDS 135.7 KB -> exactly 1 block/CU -> the 64 rec
// blocks and 192 gemm blocks co-reside on disjoint CUs. rec(p) reads Xp_cur,
// gemm writes Xp_nxt (ping-pong) -> no data overlap. proj(p+1) within a layer
// depends only on the layer input (x2 / completed Hcat), never on rec(p).
//
// blocks [0,64): rec — BYTE-IDENTICAL round-4/6 verified body.
//   whh on-chip (kp<KP_REG regs, rest LDS b128-packed); h via v_readlane.
// blocks [64,256): proj — round-6 gemm tile logic at 512 thr: the two
//   256-thread halves share the A tile and own one 64-col W tile each;
//   loops over (m-tile, n-pair, dir) units. t0n < 0 -> no gemm work.
// ---------------------------------------------------------------------------
__global__
__attribute__((amdgpu_flat_work_group_size(512, 512), amdgpu_waves_per_eu(2, 2)))
void rec_fused(
    const float* __restrict__ XpF, const float* __restrict__ XpB,
    const u32* __restrict__ whh16, const uint4* __restrict__ wp4,
    const int* __restrict__ lens,
    float* __restrict__ state, bf16_t* __restrict__ Hout, int s0, int chunk,
    const bf16_t* __restrict__ Ag, const float* __restrict__ Wg2,
    const float* __restrict__ biasg, float* __restrict__ XpFn,
    float* __restrict__ XpBn, int Kg, int t0n)
{
    __shared__ __align__(16) u32 smem[32768 + 1024 + 128];   // 135.7 KB

    const int t = threadIdx.x;        // 0..511

    if (blockIdx.x < 64) {
        // ================= recurrence (verified body) =================
        uint4* wlds4 = (uint4*)smem;
        float* gs    = (float*)(smem + 32768);
        u32*   hp    = smem + 32768 + 1024;

        const int bd   = blockIdx.x;
        const int b    = bd >> 1;
        const int d    = bd & 1;
        const int j0   = t * 2;
        const int lane = t & 63;
        const int len  = lens[b];
        const int s1   = min(s0 + chunk, len);
        const u32*   Wg = whh16 + (size_t)d * (128 * 1024);
        const uint4* Wp = wp4   + (size_t)d * (2 * NG * 512);

        uint2 w2[KP_REG];             // .x: col j0, .y: col j0+1
#pragma unroll
        for (int kp = 0; kp < KP_REG; ++kp)
            w2[kp] = *(const uint2*)(Wg + (size_t)kp * 1024 + j0);
#pragma unroll
        for (int i = 0; i < 2 * NG; ++i)
            wlds4[i * 512 + t] = Wp[i * 512 + t];

        float* st = state + bd * 512;
        float c = 0.f, hcur = 0.f;
        if (t < 256) {
            if (s0 > 0) { hcur = st[t]; c = st[256 + t]; }
            u32 hb = f2h(hcur);
            u32 ob = (u32)__shfl_xor((int)hb, 1);
            if (!(t & 1)) hp[t >> 1] = hb | (ob << 16);
        }
        __syncthreads();

        const float* xrow = ((d ? XpB : XpF) + (size_t)b * ((size_t)chunk * 1024));
        const uint4* wpA = wlds4 + t;
        const uint4* wpB = wlds4 + NG * 512 + t;
        for (int s = s0; s < s1; ++s, xrow += 1024) {
            float2 xv = *(const float2*)(xrow + j0);
            uint2 hreg = *(const uint2*)(hp + 2 * lane);
            float a0 = 0.f, a1 = 0.f, b0 = 0.f, b1 = 0.f;
#pragma unroll
            for (int kp = 0; kp < KP_REG; kp += 2) {
                u32 h0 = rl(hreg.x, kp >> 1);
                u32 h1 = rl(hreg.y, kp >> 1);
                a0 = dot2f(w2[kp].x,     h0, a0); a1 = dot2f(w2[kp].y,     h0, a1);
                b0 = dot2f(w2[kp + 1].x, h1, b0); b1 = dot2f(w2[kp + 1].y, h1, b1);
            }
#pragma unroll
            for (int g = 0; g < NG; ++g) {
                uint4 wA = wpA[g * 512];
                uint4 wB = wpB[g * 512];
                const int lb = (KP_REG >> 1) + 2 * g;
                u32 h0 = rl(hreg.x, lb);
                u32 h1 = rl(hreg.y, lb);
                u32 h2 = rl(hreg.x, lb + 1);
                u32 h3 = rl(hreg.y, lb + 1);
                a0 = dot2f(wA.x, h0, a0); a1 = dot2f(wB.x, h0, a1);
                b0 = dot2f(wA.y, h1, b0); b1 = dot2f(wB.y, h1, b1);
                a0 = dot2f(wA.z, h2, a0); a1 = dot2f(wB.z, h2, a1);
                b0 = dot2f(wA.w, h3, b0); b1 = dot2f(wB.w, h3, b1);
            }
            *(float2*)(gs + j0) = make_float2(a0 + b0 + xv.x, a1 + b1 + xv.y);
            __syncthreads();
            if (t < 256) {
                float ig = sigmoidf_(gs[t]);
                float fg = sigmoidf_(gs[256 + t]);
                float gg = tanh_(gs[512 + t]);
                float og = sigmoidf_(gs[768 + t]);
                c = fmaf(fg, c, ig * gg);
                float hn = og * tanh_(c);
                const int tau = d ? (len - 1 - s) : s;
                Hout[(size_t)(b * T_SEQ + tau) * 512 + (d << 8) + t] = f2bf(hn);
                u32 hb = f2h(hn);
                u32 ob = (u32)__shfl_xor((int)hb, 1);
                if (!(t & 1)) hp[t >> 1] = hb | (ob << 16);
                hcur = hn;
            }
            __syncthreads();
        }
        if (t < 256) { st[t] = hcur; st[256 + t] = c; }
        return;
    }

    // ================= projection GEMM for next phase =================
    if (t0n < 0) return;
    const int ngb = gridDim.x - 64;
    const int gb  = blockIdx.x - 64;
    u32* As  = smem;                  // 16*258 = 4128
    u32* Ws0 = smem + 4128;           // 16*66  = 1056
    u32* Ws1 = smem + 4128 + 1056;
    const int half = t >> 8;          // 0/1 -> own 64-col W tile
    const int ltid = t & 255;
    u32* Wsh = half ? Ws1 : Ws0;
    const int m0  = (ltid >> 3) * 8;
    const int n0l = (ltid & 7) * 8;
    const int Mc  = 32 * chunk;
    const int gxm = (Mc + 255) >> 8;
    const int U   = gxm * 8 * 2;      // (m-tile, n-pair, dir) units

    for (int u = gb; u < U; u += ngb) {
        const int dir  = u & 1;
        const int rem  = u >> 1;
        const int mt   = rem >> 3;
        const int np   = rem & 7;
        const int m_base = mt * 256;
        const int n_base = np * 128 + half * 64;
        const float* Wd = Wg2 + (size_t)dir * (1024 * (size_t)Kg);
        const float* bd = biasg + dir * 1024;
        float* Xout = dir ? XpBn : XpFn;
        float acc[8][8] = {};

        for (int k0 = 0; k0 < Kg; k0 += 32) {
            // stage A (256 rows x 32 k), all 512 threads, 4 float4s each
#pragma unroll
            for (int i = 0; i < 4; ++i) {
                int f4  = i * 512 + t;
                int row = f4 >> 3;
                int k4  = (f4 & 7) << 2;
                int gm  = m_base + row;
                int gk  = k0 + k4;
                float4 v = make_float4(0.f, 0.f, 0.f, 0.f);
                if (gm < Mc && gk < Kg) {
                    int bb = gm / chunk;
                    int rr = gm - bb * chunk;
                    int tt = dir ? (lens[bb] - 1 - (t0n + rr)) : (t0n + rr);
                    if (tt >= 0 && tt < T_SEQ)
                        v = ld4(Ag + ((size_t)(bb * T_SEQ + tt) * Kg + gk));
                }
                int kp = k4 >> 1;
                As[(kp + 0) * 258 + row] = f2h(v.x) | (f2h(v.y) << 16);
                As[(kp + 1) * 258 + row] = f2h(v.z) | (f2h(v.w) << 16);
            }
            // stage W (64 rows x 32 k) per half
#pragma unroll
            for (int i = 0; i < 2; ++i) {
                int f4  = i * 256 + ltid;
                int row = f4 >> 3;
                int k4  = (f4 & 7) << 2;
                int gn  = n_base + row;
                int gk  = k0 + k4;
                float4 v = make_float4(0.f, 0.f, 0.f, 0.f);
                if (gk < Kg)
                    v = *(const float4*)(Wd + (size_t)gn * Kg + gk);
                int kp = k4 >> 1;
                Wsh[(kp + 0) * 66 + row] = f2h(v.x) | (f2h(v.y) << 16);
                Wsh[(kp + 1) * 66 + row] = f2h(v.z) | (f2h(v.w) << 16);
            }
            __syncthreads();
#pragma unroll 8
            for (int kk = 0; kk < 16; ++kk) {
                u32 am[8], wn[8];
#pragma unroll
                for (int j = 0; j < 4; ++j) {
                    uint2 a = *(const uint2*)(As + kk * 258 + m0 + 2 * j);
                    am[2 * j] = a.x; am[2 * j + 1] = a.y;
                    uint2 w = *(const uint2*)(Wsh + kk * 66 + n0l + 2 * j);
                    wn[2 * j] = w.x; wn[2 * j + 1] = w.y;
                }
#pragma unroll
                for (int im = 0; im < 8; ++im)
#pragma unroll
                    for (int in = 0; in < 8; ++in)
                        acc[im][in] = dot2f(am[im], wn[in], acc[im][in]);
            }
            __syncthreads();
        }

        float bs[8];
#pragma unroll
        for (int j = 0; j < 8; ++j) bs[j] = bd[n_base + n0l + j];
#pragma unroll
        for (int im = 0; im < 8; ++im) {
            int gm = m_base + m0 + im;
            if (gm < Mc) {
                float* crow = Xout + (size_t)gm * 1024 + n_base + n0l;
                *(float4*)(crow)     = make_float4(acc[im][0] + bs[0], acc[im][1] + bs[1],
                                                   acc[im][2] + bs[2], acc[im][3] + bs[3]);
                *(float4*)(crow + 4) = make_float4(acc[im][4] + bs[4], acc[im][5] + bs[5],
                                                   acc[im][6] + bs[6], acc[im][7] + bs[7]);
            }
        }
    }
}

// ---------------------------------------------------------------------------
// Masked mean-pool over time (bf16 in, fp32 atomically accumulated out).
// ---------------------------------------------------------------------------
__global__ __launch_bounds__(256) void pooled_kernel(
    const bf16_t* __restrict__ L, const int* __restrict__ lens,
    float* __restrict__ pooled)
{
    const int b     = blockIdx.x;
    const int chunk = blockIdx.y;
    const int tid   = threadIdx.x;
    const int len   = lens[b];
    const int t0    = chunk * 250;
    const int t1    = min(t0 + 250, len);
    const float inv = 1.f / fmaxf((float)len, 1.f);
    float s0 = 0.f, s1 = 0.f;
    for (int t = t0; t < t1; ++t) {
        const bf16_t* row = L + (size_t)(b * T_SEQ + t) * 512;
        s0 += bf2f(row[tid]);
        s1 += bf2f(row[tid + 256]);
    }
    if (t1 > t0) {
        atomicAdd(&pooled[b * 512 + tid], s0 * inv);
        atomicAdd(&pooled[b * 512 + 256 + tid], s1 * inv);
    }
}

// ---------------------------------------------------------------------------
// Utterance head: out[b] = relu(pooled@w1.T + b1) @ w2 + b2.
// ---------------------------------------------------------------------------
__global__ __launch_bounds__(256) void utt_head(
    const float* __restrict__ pooled,
    const float* __restrict__ w1T, const float* __restrict__ b1,
    const float* __restrict__ w2, const float* __restrict__ b2,
    float* __restrict__ out)
{
    const int b   = blockIdx.x;
    const int tid = threadIdx.x;
    __shared__ float p[512];
    __shared__ float hid[512];
    __shared__ float red[4];
    p[tid]       = pooled[b * 512 + tid];
    p[tid + 256] = pooled[b * 512 + 256 + tid];
    __syncthreads();
#pragma unroll
    for (int half = 0; half < 2; ++half) {
        int u = tid + half * 256;
        float a = b1[u];
#pragma unroll 8
        for (int k = 0; k < 512; ++k) a = fmaf(w1T[(size_t)k * 512 + u], p[k], a);
        hid[u] = fmaxf(a, 0.f);
    }
    __syncthreads();
    float part = hid[tid] * w2[tid] + hid[tid + 256] * w2[tid + 256];
    for (int off = 32; off; off >>= 1) part += __shfl_down(part, off, 64);
    if ((tid & 63) == 0) red[tid >> 6] = part;
    __syncthreads();
    if (tid == 0) out[b] = red[0] + red[1] + red[2] + red[3] + b2[0];
}

// ---------------------------------------------------------------------------
// Fused segment head: mean over [st,en) of bf16 lstm_out -> relu(W1x+b1) -> w2.
// ---------------------------------------------------------------------------
__global__ __launch_bounds__(256) void seg_head(
    const bf16_t* __restrict__ L, const int* __restrict__ lens,
    const int* __restrict__ segs,
    const float* __restrict__ w1T, const float* __restrict__ b1,
    const float* __restrict__ w2, const float* __restrict__ b2,
    const int* __restrict__ seg_lens, float* __restrict__ out)
{
    const int blk = blockIdx.x;
    const int b   = blk / NSEG;
    const int s   = blk - b * NSEG;
    const int tid = threadIdx.x;
    __shared__ float m[512];
    __shared__ float hid[512];
    __shared__ float red[4];
    const int len = lens[b];
    int st = segs[blk * 2 + 0];
    int en = segs[blk * 2 + 1];
    st = min(max(st, 0), len);
    en = max(st + 1, min(en, len));
    const float inv = 1.f / (float)(en - st);
    float a0 = 0.f, a1 = 0.f;
    for (int t = st; t < en; ++t) {
        const bf16_t* row = L + (size_t)(b * T_SEQ + t) * 512;
        a0 += bf2f(row[tid]);
        a1 += bf2f(row[tid + 256]);
    }
    m[tid]       = a0 * inv;
    m[tid + 256] = a1 * inv;
    __syncthreads();
#pragma unroll
    for (int half = 0; half < 2; ++half) {
        int u = tid + half * 256;
        float a = b1[u];
#pragma unroll 8
        for (int k = 0; k < 512; ++k) a = fmaf(w1T[(size_t)k * 512 + u], m[k], a);
        hid[u] = fmaxf(a, 0.f);
    }
    __syncthreads();
    float part = hid[tid] * w2[tid] + hid[tid + 256] * w2[tid + 256];
    for (int off = 32; off; off >>= 1) part += __shfl_down(part, off, 64);
    if ((tid & 63) == 0) red[tid >> 6] = part;
    __syncthreads();
    if (tid == 0)
        out[BATCH + blk] = (s < seg_lens[b]) ? red[0] + red[1] + red[2] + red[3] + b2[0]
                                             : 0.f;
}

// ---------------------------------------------------------------------------
extern "C" void kernel_launch(void* const* d_in, const int* in_sizes, int n_in,
                              void* d_out, int out_size, void* d_ws, size_t ws_size,
                              hipStream_t stream)
{
    const float* features = (const float*)d_in[0];
    const int*   feat_len = (const int*)d_in[1];
    const int*   segs     = (const int*)d_in[2];
    const int*   seg_lens = (const int*)d_in[3];
    const float* conv1_w  = (const float*)d_in[4];
    const float* conv1_b  = (const float*)d_in[5];
    const float* conv2_w  = (const float*)d_in[6];
    const float* conv2_b  = (const float*)d_in[7];
    const float* wih0     = (const float*)d_in[8];
    const float* whh0     = (const float*)d_in[9];
    const float* bias0    = (const float*)d_in[10];
    const float* wih1     = (const float*)d_in[11];
    const float* whh1     = (const float*)d_in[12];
    const float* bias1    = (const float*)d_in[13];
    const float* seg_w1   = (const float*)d_in[14];
    const float* seg_b1   = (const float*)d_in[15];
    const float* seg_w2   = (const float*)d_in[16];
    const float* seg_b2   = (const float*)d_in[17];
    const float* utt_w1   = (const float*)d_in[18];
    const float* utt_b1   = (const float*)d_in[19];
    const float* utt_w2   = (const float*)d_in[20];
    const float* utt_b2   = (const float*)d_in[21];
    float* out = (float*)d_out;
    char*  wsb = (char*)d_ws;

    // ---- byte-granular workspace plan (256B-aligned regions) ----
    size_t off = 0;
    auto alloc = [&](size_t bytes) -> size_t {
        size_t o = off;
        off += (bytes + 255) & ~(size_t)255;
        return o;
    };
    const size_t o_wt1    = alloc(61440  * 4);            // conv1 w (256,240)
    const size_t o_wt2    = alloc(196608 * 4);            // conv2 w (256,768)
    const size_t o_whh0T  = alloc(524288 * 4);            // (2,256,1024)
    const size_t o_whh1T  = alloc(524288 * 4);
    const size_t o_w16_0  = alloc(262144 * 4);            // (2,128,1024) f16x2
    const size_t o_w16_1  = alloc(262144 * 4);
    const size_t o_wp4_0  = alloc((size_t)2 * 2 * NG * 512 * 16);  // b128-packed
    const size_t o_wp4_1  = alloc((size_t)2 * 2 * NG * 512 * 16);
    const size_t o_sw1T   = alloc(262144 * 4);            // seg w1 transposed
    const size_t o_uw1T   = alloc(262144 * 4);            // utt w1 transposed
    const size_t o_state  = alloc(32768  * 4);            // (64,512) h|c
    const size_t o_pooled = alloc(16384  * 4);
    const size_t o_Hcat   = alloc((size_t)32768000 * 2);  // bf16 (B,T,512)
    const size_t o_lstm   = alloc((size_t)32768000 * 2);  // bf16 (B,T,512)
    // y1 (bf16 B,T,256) and x2 (bf16 B,T,256) alias inside the lstm region:
    // both are dead before the layer-1 recurrence writes lstm_out.
    const size_t o_y1     = o_lstm;
    const size_t o_x2     = o_lstm + (size_t)16384000 * 2;
    const size_t fixed_end = off;

    // ---- pick the largest chunk whose 4 Xp buffers (ping-pong F/B) fit ----
    const int cands[] = {250, 200, 125, 100, 50, 40, 25, 20, 10};
    int chunk = 0;
    size_t o_Xp[2][2] = {};
    for (int ci = 0; ci < 9; ++ci) {
        int c = cands[ci];
        size_t xp_bytes = ((size_t)c * 32 * 1024 * 4 + 255) & ~(size_t)255;
        if (fixed_end + 4 * xp_bytes <= ws_size) {
            chunk = c;
            o_Xp[0][0] = fixed_end;
            o_Xp[0][1] = fixed_end + xp_bytes;
            o_Xp[1][0] = fixed_end + 2 * xp_bytes;
            o_Xp[1][1] = fixed_end + 3 * xp_bytes;
            break;
        }
    }
    if (chunk == 0) {
        ws_guard_kernel<<<(out_size + 255) / 256, 256, 0, stream>>>(out, out_size);
        return;
    }
    const int nph = T_SEQ / chunk;

    float*  wt1    = (float*)(wsb + o_wt1);
    float*  wt2    = (float*)(wsb + o_wt2);
    float*  whh0T  = (float*)(wsb + o_whh0T);
    float*  whh1T  = (float*)(wsb + o_whh1T);
    u32*    w16_0  = (u32*)(wsb + o_w16_0);
    u32*    w16_1  = (u32*)(wsb + o_w16_1);
    u32*    wp4_0  = (u32*)(wsb + o_wp4_0);
    u32*    wp4_1  = (u32*)(wsb + o_wp4_1);
    float*  sw1T   = (float*)(wsb + o_sw1T);
    float*  uw1T   = (float*)(wsb + o_uw1T);
    float*  state  = (float*)(wsb + o_state);
    float*  pooled = (float*)(wsb + o_pooled);
    bf16_t* Hcat   = (bf16_t*)(wsb + o_Hcat);
    bf16_t* lstm   = (bf16_t*)(wsb + o_lstm);
    bf16_t* y1     = (bf16_t*)(wsb + o_y1);
    bf16_t* x2     = (bf16_t*)(wsb + o_x2);
    float*  XpF[2] = { (float*)(wsb + o_Xp[0][0]), (float*)(wsb + o_Xp[1][0]) };
    float*  XpB[2] = { (float*)(wsb + o_Xp[0][1]), (float*)(wsb + o_Xp[1][1]) };

    hipMemsetAsync(state, 0, 32768 * 4, stream);
    hipMemsetAsync(pooled, 0, 16384 * 4, stream);

    // weight re-layouts
    transpose3<<<240, 256, 0, stream>>>(conv1_w, wt1, 256, 80, 3);
    transpose3<<<768, 256, 0, stream>>>(conv2_w, wt2, 256, 256, 3);
    transpose3<<<2048, 256, 0, stream>>>(whh0, whh0T, 2, 1024, 256);
    transpose3<<<2048, 256, 0, stream>>>(whh1, whh1T, 2, 1024, 256);
    transpose3<<<1024, 256, 0, stream>>>(seg_w1, sw1T, 1, 512, 512);
    transpose3<<<1024, 256, 0, stream>>>(utt_w1, uw1T, 1, 512, 512);
    pack_whh<<<1024, 256, 0, stream>>>(whh0T, w16_0, wp4_0);
    pack_whh<<<1024, 256, 0, stream>>>(whh1T, w16_1, wp4_1);

    // conv1: (B,T,80) -> bf16 (B,T,256), relu
    gemm_nt<1, 80, float, true><<<dim3(250, 4), 256, 0, stream>>>(
        features, wt1, conv1_b, y1, nullptr, 64000, 256, 240, 1, 0, 0, feat_len);
    // conv2: bf16 (B,T,256) -> bf16 (B,T,256), relu
    gemm_nt<1, 256, bf16_t, true><<<dim3(250, 4), 256, 0, stream>>>(
        y1, wt2, conv2_b, x2, nullptr, 64000, 256, 768, 1, 0, 0, feat_len);

    const int gx = (32 * chunk + 255) / 256;
    const int Mc = 32 * chunk;

    // ---- layer 0: proj(0) standalone, then fused rec(p)+proj(p+1) ----
    gemm_nt<4, 1, bf16_t, false><<<dim3(gx, 16, 2), 256, 0, stream>>>(
        x2, wih0, bias0, XpF[0], XpB[0], Mc, 1024, 256, 0, 0, chunk, feat_len);
    for (int p = 0; p < nph; ++p) {
        const int t0n = (p + 1 < nph) ? (p + 1) * chunk : -1;
        rec_fused<<<256, 512, 0, stream>>>(
            XpF[p & 1], XpB[p & 1], w16_0, (const uint4*)wp4_0, feat_len,
            state, Hcat, p * chunk, chunk,
            x2, wih0, bias0, XpF[(p + 1) & 1], XpB[(p + 1) & 1], 256, t0n);
    }

    // reset recurrent state for layer 1
    hipMemsetAsync(state, 0, 32768 * 4, stream);

    // ---- layer 1: proj(0) standalone (needs full Hcat), then fused ----
    gemm_nt<4, 1, bf16_t, false><<<dim3(gx, 16, 2), 256, 0, stream>>>(
        Hcat, wih1, bias1, XpF[0], XpB[0], Mc, 1024, 512, 0, 0, chunk, feat_len);
    for (int p = 0; p < nph; ++p) {
        const int t0n = (p + 1 < nph) ? (p + 1) * chunk : -1;
        rec_fused<<<256, 512, 0, stream>>>(
            XpF[p & 1], XpB[p & 1], w16_1, (const uint4*)wp4_1, feat_len,
            state, lstm, p * chunk, chunk,
            Hcat, wih1, bias1, XpF[(p + 1) & 1], XpB[(p + 1) & 1], 512, t0n);
    }

    // pooled mean + utterance head
    pooled_kernel<<<dim3(32, 8), 256, 0, stream>>>(lstm, feat_len, pooled);
    utt_head<<<32, 256, 0, stream>>>(pooled, uw1T, utt_b1, utt_w2, utt_b2, out);

    // fused segment means + head
    seg_head<<<3200, 256, 0, stream>>>(lstm, feat_len, segs, sw1T, seg_b1,
                                       seg_w2, seg_b2, seg_lens, out);
}